// Round 9
// baseline (363.707 us; speedup 1.0000x reference)
//
#include <hip/hip_runtime.h>
#include <hip/hip_bf16.h>

#define IN_DIM 128
#define HID 256
#define BN_EPS 1e-5f

typedef __attribute__((ext_vector_type(8))) short bf16x8;
typedef __attribute__((ext_vector_type(16))) float f32x16;
typedef __attribute__((ext_vector_type(2))) float f32x2;

// ---------- helpers ----------
__device__ __forceinline__ float ld_f(const void* p, size_t i, int bf16) {
  if (bf16) return __bfloat162float(((const __hip_bfloat16*)p)[i]);
  return ((const float*)p)[i];
}
__device__ __forceinline__ float blo(unsigned u) { return __uint_as_float(u << 16); }
__device__ __forceinline__ float bhi(unsigned u) { return __uint_as_float(u & 0xffff0000u); }
__device__ __forceinline__ unsigned short f2bf(float f) {
  __hip_bfloat16 b = __float2bfloat16(f);
  return __builtin_bit_cast(unsigned short, b);
}
__device__ __forceinline__ void load_lds16(const void* g, void* l) {
  __builtin_amdgcn_global_load_lds((const __attribute__((address_space(1))) void*)g,
                                   (__attribute__((address_space(3))) void*)l, 16, 0, 0);
}
// order-preserving float->uint key (monotone increasing); init 0 is neutral for max
__device__ __forceinline__ unsigned fkey(float v) {
  unsigned s = __float_as_uint(v);
  return (s & 0x80000000u) ? ~s : (s | 0x80000000u);
}
__device__ __forceinline__ float finv(unsigned k) {
  unsigned s = (k & 0x80000000u) ? (k ^ 0x80000000u) : ~k;
  return __uint_as_float(s);
}

// ---------- mega prep: flag detect + histogram (stores per-edge rank!) + x->A1/X8 + W packs ----------
__global__ void prep_kernel(
    const void* __restrict__ x, const void* __restrict__ ei,
    const void* Wl_f1, const void* bl_f1, const void* Wr_f1,
    const void* Wl_b1, const void* bl_b1, const void* Wr_b1,
    const void* Wl_f2, const void* bl_f2, const void* Wr_f2,
    const void* Wl_b2, const void* bl_b2, const void* Wr_b2,
    const void* g1, const void* be1, const void* g2, const void* be2,
    int* __restrict__ degf, int* __restrict__ degb,
    int* __restrict__ rankf, int* __restrict__ rankb,
    __hip_bfloat16* __restrict__ A1,
    unsigned char* __restrict__ X8,
    __hip_bfloat16* __restrict__ Wpk1, float* __restrict__ b1,
    __hip_bfloat16* __restrict__ Wpk2, float* __restrict__ b2,
    float* __restrict__ gamma1, float* __restrict__ beta1,
    float* __restrict__ gamma2, float* __restrict__ beta2,
    int n_nodes, int n_edges) {
  __shared__ int votes, nz;
  if (threadIdx.x == 0) { votes = 0; nz = 0; }
  __syncthreads();
  {
    unsigned e = (((const unsigned*)x)[threadIdx.x] >> 7) & 0xFFu;
    if (e >= 100u && e <= 140u) atomicAdd(&votes, 1);
    if (((const unsigned*)ei)[2 * threadIdx.x + 1] != 0u) atomicAdd(&nz, 1);
  }
  __syncthreads();
  const int bf = (votes > 128) ? 1 : 0;
  const int i32 = (nz > 0) ? 1 : 0;
  const int tid = blockIdx.x * 256 + threadIdx.x;
  const int nt = gridDim.x * 256;
  for (int i = tid; i < n_edges; i += nt) {
    int s, d;
    if (i32) { s = ((const int*)ei)[i]; d = ((const int*)ei)[n_edges + i]; }
    else     { s = (int)((const long long*)ei)[i]; d = (int)((const long long*)ei)[n_edges + i]; }
    rankf[i] = atomicAdd(&degf[d], 1);
    rankb[i] = atomicAdd(&degb[s], 1);
  }
  // x -> bf16 self-slice of A1 (exact path through Wr) AND dense fp8 X8 (gather source)
  const size_t nq = (size_t)n_nodes * IN_DIM / 4;
  for (size_t q = tid; q < nq; q += nt) {
    const int row = (int)(q >> 5), j = (int)(q & 31) * 4;
    __hip_bfloat16* dstp = A1 + (size_t)row * 384 + 256 + j;
    float f0, f1, f2, f3;
    if (bf) {
      uint2 v = ((const uint2*)x)[q];
      *(uint2*)dstp = v;
      f0 = blo(v.x); f1 = bhi(v.x); f2 = blo(v.y); f3 = bhi(v.y);
    } else {
      float4 v = ((const float4*)x)[q];
      unsigned short o[4] = {f2bf(v.x), f2bf(v.y), f2bf(v.z), f2bf(v.w)};
      *(uint2*)dstp = *(uint2*)o;
      f0 = v.x; f1 = v.y; f2 = v.z; f3 = v.w;
    }
    int p8 = __builtin_amdgcn_cvt_pk_fp8_f32(f0, f1, 0, false);
    p8 = __builtin_amdgcn_cvt_pk_fp8_f32(f2, f3, p8, true);
    *(int*)(X8 + (size_t)row * 128 + j) = p8;
  }
  for (int idx = tid; idx < 768 * 256; idx += nt) {
    {
      int j = idx & 7, l = (idx >> 3) & 63, rest = idx >> 9;
      int s = rest % 48, t = rest / 48;
      int k = s * 16 + (l >> 5) * 8 + j, col = t * 32 + (l & 31);
      float v;
      if (k < 256)      v = ld_f(Wl_f2, (size_t)k * 256 + col, bf);
      else if (k < 512) v = ld_f(Wl_b2, (size_t)(k - 256) * 256 + col, bf);
      else              v = ld_f(Wr_f2, (size_t)(k - 512) * 256 + col, bf) +
                            ld_f(Wr_b2, (size_t)(k - 512) * 256 + col, bf);
      Wpk2[idx] = __float2bfloat16(v);
    }
    if (idx < 384 * 256) {
      int j = idx & 7, l = (idx >> 3) & 63, rest = idx >> 9;
      int s = rest % 24, t = rest / 24;
      int k = s * 16 + (l >> 5) * 8 + j, col = t * 32 + (l & 31);
      float v;
      if (k < 128)      v = ld_f(Wl_f1, (size_t)k * 256 + col, bf);
      else if (k < 256) v = ld_f(Wl_b1, (size_t)(k - 128) * 256 + col, bf);
      else              v = ld_f(Wr_f1, (size_t)(k - 256) * 256 + col, bf) +
                            ld_f(Wr_b1, (size_t)(k - 256) * 256 + col, bf);
      Wpk1[idx] = __float2bfloat16(v);
    }
    if (idx < 256) {
      b1[idx] = ld_f(bl_f1, idx, bf) + ld_f(bl_b1, idx, bf);
      b2[idx] = ld_f(bl_f2, idx, bf) + ld_f(bl_b2, idx, bf);
      gamma1[idx] = ld_f(g1, idx, bf);
      beta1[idx]  = ld_f(be1, idx, bf);
      gamma2[idx] = ld_f(g2, idx, bf);
      beta2[idx]  = ld_f(be2, idx, bf);
    }
  }
}

// ---------- CSR build ----------
__global__ void scan_part_kernel(const int* __restrict__ degf, const int* __restrict__ degb,
                                 int* __restrict__ offf, int* __restrict__ offb,
                                 int* __restrict__ partials, int n, int nb) {
  __shared__ int buf[256];
  const int b = blockIdx.x;
  const int* deg = (b < nb) ? degf : degb;
  int* off = (b < nb) ? offf : offb;
  const int chunk = (b < nb) ? b : (b - nb);
  const int i = chunk * 256 + threadIdx.x;
  int v = (i < n) ? deg[i] : 0;
  buf[threadIdx.x] = v;
  __syncthreads();
  for (int s = 1; s < 256; s <<= 1) {
    int t = (threadIdx.x >= s) ? buf[threadIdx.x - s] : 0;
    __syncthreads();
    buf[threadIdx.x] += t;
    __syncthreads();
  }
  if (i < n) off[i] = buf[threadIdx.x] - v;
  if (threadIdx.x == 255) partials[b] = buf[255];
}

__global__ void scan_add_kernel(int* __restrict__ offf, int* __restrict__ offb,
                                const int* __restrict__ partials, int n, int nb, int n_edges) {
  __shared__ int red[256];
  const int b = blockIdx.x;
  int* off = (b < nb) ? offf : offb;
  const int chunk = (b < nb) ? b : (b - nb);
  const int abase = (b < nb) ? 0 : nb;
  int v = (threadIdx.x < chunk) ? partials[abase + threadIdx.x] : 0;
  red[threadIdx.x] = v;
  __syncthreads();
  for (int s = 128; s > 0; s >>= 1) {
    if (threadIdx.x < s) red[threadIdx.x] += red[threadIdx.x + s];
    __syncthreads();
  }
  const int prefix = red[0];
  const int i = chunk * 256 + threadIdx.x;
  if (i < n) off[i] += prefix;
  if (b == 0 && threadIdx.x == 0) { offf[n] = n_edges; offb[n] = n_edges; }
}

// ---------- atomic-free edge placement ----------
__global__ void fill_adj_kernel(const void* __restrict__ ei,
                                const int* __restrict__ rankf, const int* __restrict__ rankb,
                                const int* __restrict__ offf, const int* __restrict__ offb,
                                int* __restrict__ adjf, int* __restrict__ adjb, int n_edges) {
  __shared__ int nz;
  if (threadIdx.x == 0) nz = 0;
  __syncthreads();
  if (((const unsigned*)ei)[2 * threadIdx.x + 1] != 0u) atomicAdd(&nz, 1);
  __syncthreads();
  const int i32 = nz > 0;
  int i = blockIdx.x * 256 + threadIdx.x;
  if (i >= n_edges) return;
  int s, d;
  if (i32) { s = ((const int*)ei)[i]; d = ((const int*)ei)[n_edges + i]; }
  else     { s = (int)((const long long*)ei)[i]; d = (int)((const long long*)ei)[n_edges + i]; }
  adjf[offf[d] + rankf[i]] = s;
  adjb[offb[s] + rankb[i]] = d;
}

// ---------- gather-mean fp8, layer 1: X8[n][128] -> bf16 mean slices of A1 ----------
__global__ __launch_bounds__(256) void gather_mean_x8_kernel(
    const unsigned char* __restrict__ Q,  // [n_nodes][128] fp8 e4m3
    __hip_bfloat16* __restrict__ A1,      // row stride 384
    const int* __restrict__ adjf, const int* __restrict__ offf,
    const int* __restrict__ adjb, const int* __restrict__ offb, int n_nodes) {
  const int gw = (int)(((size_t)blockIdx.x * 256 + threadIdx.x) >> 6);
  const int lane = threadIdx.x & 63;
  if (gw >= 2 * n_nodes) return;
  int node, dir;
  const int *adj, *off;
  if (gw < n_nodes) { node = gw;           adj = adjf; off = offf; dir = 0; }
  else              { node = gw - n_nodes; adj = adjb; off = offb; dir = 1; }
  const int s = off[node], e = off[node + 1];
  const int sub = lane >> 4, cl = lane & 15;  // 4 subs x 16 col-lanes (8 cols each)
  auto clampi = [&](int i) { return max(min(i, e - 1), 0); };
  auto ROW = [&](int a) { return *(const uint2*)(Q + (size_t)a * 128 + cl * 8); };
  float acc[8] = {0.f, 0.f, 0.f, 0.f, 0.f, 0.f, 0.f, 0.f};
  int i = s + sub;
  int a0 = adj[clampi(i)];
  int a1 = adj[clampi(i + 4)];
  int a2 = adj[clampi(i + 8)];
  int a3 = adj[clampi(i + 12)];
  uint2 r0 = ROW(a0);
  uint2 r1 = ROW(a1);
  for (; i < e; i += 8) {
    const uint2 r2 = ROW(a2), r3 = ROW(a3);  // next pair in flight
    const int a4 = adj[clampi(i + 16)];
    const int a5 = adj[clampi(i + 20)];
    {
      f32x2 p;
      p = __builtin_amdgcn_cvt_pk_f32_fp8((int)r0.x, false); acc[0] += p.x; acc[1] += p.y;
      p = __builtin_amdgcn_cvt_pk_f32_fp8((int)r0.x, true);  acc[2] += p.x; acc[3] += p.y;
      p = __builtin_amdgcn_cvt_pk_f32_fp8((int)r0.y, false); acc[4] += p.x; acc[5] += p.y;
      p = __builtin_amdgcn_cvt_pk_f32_fp8((int)r0.y, true);  acc[6] += p.x; acc[7] += p.y;
    }
    if (i + 4 < e) {
      f32x2 p;
      p = __builtin_amdgcn_cvt_pk_f32_fp8((int)r1.x, false); acc[0] += p.x; acc[1] += p.y;
      p = __builtin_amdgcn_cvt_pk_f32_fp8((int)r1.x, true);  acc[2] += p.x; acc[3] += p.y;
      p = __builtin_amdgcn_cvt_pk_f32_fp8((int)r1.y, false); acc[4] += p.x; acc[5] += p.y;
      p = __builtin_amdgcn_cvt_pk_f32_fp8((int)r1.y, true);  acc[6] += p.x; acc[7] += p.y;
    }
    r0 = r2; r1 = r3; a2 = a4; a3 = a5;
  }
#pragma unroll
  for (int o = 32; o >= 16; o >>= 1) {
#pragma unroll
    for (int k = 0; k < 8; ++k) acc[k] += __shfl_xor(acc[k], o, 64);
  }
  if (sub == 0) {
    const float inv = 1.0f / (float)max(e - s, 1);
    union { unsigned short us[8]; uint4 v; } o;
#pragma unroll
    for (int k = 0; k < 8; ++k) o.us[k] = f2bf(acc[k] * inv);
    *(uint4*)(A1 + (size_t)node * 384 + dir * 128 + cl * 8) = o.v;
  }
}

// ---------- gather-mean fp8, layer 2 (r5-measured; unchanged) ----------
__global__ __launch_bounds__(256) void gather_mean_q8_kernel(
    const unsigned char* __restrict__ Q,  // [n_nodes][256] fp8 e4m3
    __hip_bfloat16* __restrict__ A,       // A2, row stride 768
    const int* __restrict__ adjf, const int* __restrict__ offf,
    const int* __restrict__ adjb, const int* __restrict__ offb, int n_nodes) {
  const int gw = (int)(((size_t)blockIdx.x * 256 + threadIdx.x) >> 6);
  const int lane = threadIdx.x & 63;
  if (gw >= 2 * n_nodes) return;
  int node, dir;
  const int *adj, *off;
  if (gw < n_nodes) { node = gw;           adj = adjf; off = offf; dir = 0; }
  else              { node = gw - n_nodes; adj = adjb; off = offb; dir = 1; }
  const int s = off[node], e = off[node + 1];
  const int sub = lane >> 5, cl = lane & 31;
  auto clampi = [&](int i) { return max(min(i, e - 1), 0); };
  auto ROW = [&](int a) { return *(const uint2*)(Q + (size_t)a * 256 + cl * 8); };
  float acc[8] = {0.f, 0.f, 0.f, 0.f, 0.f, 0.f, 0.f, 0.f};
  int i = s + sub;
  int a0 = adj[clampi(i)];
  int a1 = adj[clampi(i + 2)];
  int a2 = adj[clampi(i + 4)];
  int a3 = adj[clampi(i + 6)];
  uint2 r0 = ROW(a0);
  uint2 r1 = ROW(a1);
  for (; i < e; i += 4) {
    const uint2 r2 = ROW(a2), r3 = ROW(a3);
    const int a4 = adj[clampi(i + 8)];
    const int a5 = adj[clampi(i + 10)];
    {
      f32x2 p;
      p = __builtin_amdgcn_cvt_pk_f32_fp8((int)r0.x, false); acc[0] += p.x; acc[1] += p.y;
      p = __builtin_amdgcn_cvt_pk_f32_fp8((int)r0.x, true);  acc[2] += p.x; acc[3] += p.y;
      p = __builtin_amdgcn_cvt_pk_f32_fp8((int)r0.y, false); acc[4] += p.x; acc[5] += p.y;
      p = __builtin_amdgcn_cvt_pk_f32_fp8((int)r0.y, true);  acc[6] += p.x; acc[7] += p.y;
    }
    if (i + 2 < e) {
      f32x2 p;
      p = __builtin_amdgcn_cvt_pk_f32_fp8((int)r1.x, false); acc[0] += p.x; acc[1] += p.y;
      p = __builtin_amdgcn_cvt_pk_f32_fp8((int)r1.x, true);  acc[2] += p.x; acc[3] += p.y;
      p = __builtin_amdgcn_cvt_pk_f32_fp8((int)r1.y, false); acc[4] += p.x; acc[5] += p.y;
      p = __builtin_amdgcn_cvt_pk_f32_fp8((int)r1.y, true);  acc[6] += p.x; acc[7] += p.y;
    }
    r0 = r2; r1 = r3; a2 = a4; a3 = a5;
  }
#pragma unroll
  for (int k = 0; k < 8; ++k) acc[k] += __shfl_xor(acc[k], 32, 64);
  if (sub == 0) {
    const float inv = 1.0f / (float)max(e - s, 1);
    union { unsigned short us[8]; uint4 v; } o;
#pragma unroll
    for (int k = 0; k < 8; ++k) o.us[k] = f2bf(acc[k] * inv);
    *(uint4*)(A + (size_t)node * 768 + dir * 256 + cl * 8) = o.v;
  }
}

// ---------- MFMA GEMM, M128 tile (r5 measured-best for layer 1; unchanged) ----------
template <int K, bool STORE>
__global__ __launch_bounds__(256, 2) void gemm_mfma128_kernel(
    const __hip_bfloat16* __restrict__ A, const __hip_bfloat16* __restrict__ Wpk,
    const float* __restrict__ bias, __hip_bfloat16* __restrict__ Cb,
    float* __restrict__ bnsum, float* __restrict__ bnsum2,
    unsigned* __restrict__ gmax, unsigned* __restrict__ gmin, int M) {
  constexpr int S = K / 16;
  constexpr int NIT = K / 128;
  __shared__ __align__(16) union SMem {
    char at[2][32768];
    struct { float colsum[256], colsum2[256]; unsigned cmax[256], cmin[256]; } st;
  } sm;
  const int wave = threadIdx.x >> 6, lane = threadIdx.x & 63;
  const int rw = wave >> 1, cw = wave & 1;
  const int rbase = blockIdx.x * 128;
  const char* gsrc = (const char*)(A + (size_t)(rbase + wave * 32 + (lane & 31)) * K)
                   + (lane >> 5) * 16;
  char* lb[2] = { &sm.at[0][wave * 1024], &sm.at[1][wave * 1024] };

  {
#pragma unroll
    for (int d = 0; d < 8; ++d) load_lds16(gsrc + d * 32, lb[0] + d * 4096);
  }

  const __hip_bfloat16* wbase = Wpk + ((size_t)(cw * 4) * S * 64 + lane) * 8;
  f32x16 acc[2][4] = {};

  for (int kb = 0; kb < NIT; ++kb) {
    __syncthreads();
    if (kb + 1 < NIT) {
      const char* g = gsrc + (size_t)(kb + 1) * 256;
      char* l = lb[(kb + 1) & 1];
#pragma unroll
      for (int d = 0; d < 8; ++d) load_lds16(g + d * 32, l + d * 4096);
    }
    const char* ab = sm.at[kb & 1];
#pragma unroll
    for (int s = 0; s < 8; ++s) {
      const int ks = kb * 8 + s;
      const bf16x8 a0 = *(const bf16x8*)(ab + (s * 4 + rw * 2 + 0) * 1024 + lane * 16);
      const bf16x8 a1 = *(const bf16x8*)(ab + (s * 4 + rw * 2 + 1) * 1024 + lane * 16);
      const bf16x8 w0 = *(const bf16x8*)(wbase + ((size_t)0 * S + ks) * 512);
      const bf16x8 w1 = *(const bf16x8*)(wbase + ((size_t)1 * S + ks) * 512);
      const bf16x8 w2 = *(const bf16x8*)(wbase + ((size_t)2 * S + ks) * 512);
      const bf16x8 w3 = *(const bf16x8*)(wbase + ((size_t)3 * S + ks) * 512);
      acc[0][0] = __builtin_amdgcn_mfma_f32_32x32x16_bf16(a0, w0, acc[0][0], 0, 0, 0);
      acc[0][1] = __builtin_amdgcn_mfma_f32_32x32x16_bf16(a0, w1, acc[0][1], 0, 0, 0);
      acc[0][2] = __builtin_amdgcn_mfma_f32_32x32x16_bf16(a0, w2, acc[0][2], 0, 0, 0);
      acc[0][3] = __builtin_amdgcn_mfma_f32_32x32x16_bf16(a0, w3, acc[0][3], 0, 0, 0);
      acc[1][0] = __builtin_amdgcn_mfma_f32_32x32x16_bf16(a1, w0, acc[1][0], 0, 0, 0);
      acc[1][1] = __builtin_amdgcn_mfma_f32_32x32x16_bf16(a1, w1, acc[1][1], 0, 0, 0);
      acc[1][2] = __builtin_amdgcn_mfma_f32_32x32x16_bf16(a1, w2, acc[1][2], 0, 0, 0);
      acc[1][3] = __builtin_amdgcn_mfma_f32_32x32x16_bf16(a1, w3, acc[1][3], 0, 0, 0);
    }
  }

  __syncthreads();
  sm.st.colsum[threadIdx.x] = 0.f;
  sm.st.colsum2[threadIdx.x] = 0.f;
  if (!STORE) { sm.st.cmax[threadIdx.x] = 0u; sm.st.cmin[threadIdx.x] = 0u; }
  __syncthreads();

#pragma unroll
  for (int rh = 0; rh < 2; ++rh) {
#pragma unroll
    for (int t = 0; t < 4; ++t) {
      const int col = cw * 128 + t * 32 + (lane & 31);
      const float bj = bias[col];
      float ls = 0.f, ls2 = 0.f, lmax = -INFINITY, lmin = INFINITY;
#pragma unroll
      for (int r = 0; r < 16; ++r) {
        const int row = rbase + rw * 64 + rh * 32 + (r & 3) + 8 * (r >> 2) + 4 * (lane >> 5);
        if (row < M) {
          float v = acc[rh][t][r] + bj;
          if (STORE) Cb[(size_t)row * 768 + 512 + col] = __float2bfloat16(v);
          ls += v;
          ls2 = fmaf(v, v, ls2);
          if (!STORE) { lmax = fmaxf(lmax, v); lmin = fminf(lmin, v); }
        }
      }
      atomicAdd(&sm.st.colsum[col], ls);
      atomicAdd(&sm.st.colsum2[col], ls2);
      if (!STORE) {
        atomicMax(&sm.st.cmax[col], fkey(lmax));
        atomicMax(&sm.st.cmin[col], ~fkey(lmin));
      }
    }
  }
  __syncthreads();
  atomicAdd(&bnsum[threadIdx.x], sm.st.colsum[threadIdx.x]);
  atomicAdd(&bnsum2[threadIdx.x], sm.st.colsum2[threadIdx.x]);
  if (!STORE) {
    atomicMax(&gmax[threadIdx.x], sm.st.cmax[threadIdx.x]);
    atomicMax(&gmin[threadIdx.x], sm.st.cmin[threadIdx.x]);
  }
}

// ---------- MFMA GEMM, M32 tile, single-barrier full-K staging ----------
// r8 diagnosis: the per-BK __syncthreads() must drain vmcnt(0) for the staging DMAs,
// which ALSO drains in-flight W register loads -> no W pipeline can survive a barrier
// (VGPR 56->60 showed the compiler collapsed the rotating buffer). Fix: M32 tile makes
// the FULL-K A-tile 32x768x2B = 48KB -> stage everything up front, ONE barrier, then 48
// barrier-free k-steps where the compiler can pipeline W loads arbitrarily deep.
// 48KB LDS -> 3 blocks/CU for TLP over the initial staging latency.
template <int K, bool STORE>
__global__ __launch_bounds__(256, 3) void gemm_mfma32_kernel(
    const __hip_bfloat16* __restrict__ A, const __hip_bfloat16* __restrict__ Wpk,
    const float* __restrict__ bias, __hip_bfloat16* __restrict__ Cb,
    float* __restrict__ bnsum, float* __restrict__ bnsum2,
    unsigned* __restrict__ gmax, unsigned* __restrict__ gmin, int M) {
  constexpr int S = K / 16;  // 48 microtiles of 1KB
  __shared__ __align__(16) union SMem {
    char at[S * 1024];
    struct { float colsum[256], colsum2[256]; unsigned cmax[256], cmin[256]; } st;
  } sm;
  const int wave = threadIdx.x >> 6, lane = threadIdx.x & 63;
  const int rbase = blockIdx.x * 32;
  // lane i -> row (i&31), k-chunk (i>>5)*8 elems of each 16-elem k-step
  const char* gsrc = (const char*)(A + (size_t)(rbase + (lane & 31)) * K) + (lane >> 5) * 16;

  // stage all S microtiles (S/4 per wave); the ONLY barrier follows
#pragma unroll
  for (int d = 0; d < S / 4; ++d) {
    const int ks = wave * (S / 4) + d;
    load_lds16(gsrc + ks * 32, &sm.at[ks * 1024]);
  }

  const __hip_bfloat16* wbase = Wpk + ((size_t)(wave * 2) * S * 64 + lane) * 8;
  f32x16 acc[2] = {};
  __syncthreads();  // drains staging DMAs once; inner loop is barrier-free

#pragma unroll 12
  for (int ks = 0; ks < S; ++ks) {
    const bf16x8 a0 = *(const bf16x8*)(&sm.at[ks * 1024] + (size_t)lane * 16);
    const bf16x8 w0 = *(const bf16x8*)(wbase + ((size_t)0 * S + ks) * 512);
    const bf16x8 w1 = *(const bf16x8*)(wbase + ((size_t)1 * S + ks) * 512);
    acc[0] = __builtin_amdgcn_mfma_f32_32x32x16_bf16(a0, w0, acc[0], 0, 0, 0);
    acc[1] = __builtin_amdgcn_mfma_f32_32x32x16_bf16(a0, w1, acc[1], 0, 0, 0);
  }

  __syncthreads();  // all waves done reading Atile; safe to alias as stats
  sm.st.colsum[threadIdx.x] = 0.f;
  sm.st.colsum2[threadIdx.x] = 0.f;
  if (!STORE) { sm.st.cmax[threadIdx.x] = 0u; sm.st.cmin[threadIdx.x] = 0u; }
  __syncthreads();

#pragma unroll
  for (int t = 0; t < 2; ++t) {
    const int col = wave * 64 + t * 32 + (lane & 31);
    const float bj = bias[col];
    float ls = 0.f, ls2 = 0.f, lmax = -INFINITY, lmin = INFINITY;
#pragma unroll
    for (int r = 0; r < 16; ++r) {
      const int row = rbase + (r & 3) + 8 * (r >> 2) + 4 * (lane >> 5);
      if (row < M) {
        float v = acc[t][r] + bj;
        if (STORE) Cb[(size_t)row * 768 + 512 + col] = __float2bfloat16(v);
        ls += v;
        ls2 = fmaf(v, v, ls2);
        if (!STORE) { lmax = fmaxf(lmax, v); lmin = fminf(lmin, v); }
      }
    }
    atomicAdd(&sm.st.colsum[col], ls);
    atomicAdd(&sm.st.colsum2[col], ls2);
    if (!STORE) {
      atomicMax(&sm.st.cmax[col], fkey(lmax));
      atomicMax(&sm.st.cmin[col], ~fkey(lmin));
    }
  }
  __syncthreads();
  atomicAdd(&bnsum[threadIdx.x], sm.st.colsum[threadIdx.x]);
  atomicAdd(&bnsum2[threadIdx.x], sm.st.colsum2[threadIdx.x]);
  if (!STORE) {
    atomicMax(&gmax[threadIdx.x], sm.st.cmax[threadIdx.x]);
    atomicMax(&gmin[threadIdx.x], sm.st.cmin[threadIdx.x]);
  }
}

// ---------- BN+ReLU in place on A2 self-slice + fp8 shadow for the layer-2 gather ----------
__global__ void bn_apply_kernel(__hip_bfloat16* __restrict__ A2,
                                unsigned char* __restrict__ A2q,
                                const float* __restrict__ sum, const float* __restrict__ sumsq,
                                const float* __restrict__ gamma, const float* __restrict__ beta,
                                int n_nodes, float inv_n) {
  const int j0 = (threadIdx.x & 63) * 4;
  const int row = blockIdx.x * 4 + (threadIdx.x >> 6);
  if (row >= n_nodes) return;
  float g[4], b[4];
#pragma unroll
  for (int k = 0; k < 4; ++k) {
    const int j = j0 + k;
    float mu = sum[j] * inv_n;
    float rs = rsqrtf(fmaxf(sumsq[j] * inv_n - mu * mu, 0.f) + BN_EPS);
    g[k] = gamma[j] * rs;
    b[k] = fmaf(-mu, g[k], beta[j]);
  }
  uint2* p = (uint2*)(A2 + (size_t)row * 768 + 512 + j0);
  uint2 w = *p;
  float h[4];
  h[0] = fmaxf(fmaf(blo(w.x), g[0], b[0]), 0.f);
  h[1] = fmaxf(fmaf(bhi(w.x), g[1], b[1]), 0.f);
  h[2] = fmaxf(fmaf(blo(w.y), g[2], b[2]), 0.f);
  h[3] = fmaxf(fmaf(bhi(w.y), g[3], b[3]), 0.f);
  unsigned short us[4] = {f2bf(h[0]), f2bf(h[1]), f2bf(h[2]), f2bf(h[3])};
  *p = *(uint2*)us;
  int q8 = __builtin_amdgcn_cvt_pk_fp8_f32(h[0], h[1], 0, false);
  q8 = __builtin_amdgcn_cvt_pk_fp8_f32(h[2], h[3], q8, true);
  *(int*)(A2q + (size_t)row * 256 + j0) = q8;
}

// ---------- finalize ----------
__global__ void finalize_kernel(const unsigned* __restrict__ xw,
                                const float* __restrict__ sum, const float* __restrict__ sumsq,
                                const unsigned* __restrict__ gmax, const unsigned* __restrict__ gmin,
                                const float* __restrict__ gamma, const float* __restrict__ beta,
                                float inv_n, void* __restrict__ out, int out_size) {
  __shared__ int votes;
  if (threadIdx.x == 0) votes = 0;
  __syncthreads();
  unsigned e = (xw[threadIdx.x] >> 7) & 0xFFu;
  if (e >= 100u && e <= 140u) atomicAdd(&votes, 1);
  __syncthreads();
  int bf = votes > 128;
  int j = threadIdx.x;
  if (j >= out_size) return;
  float mu = sum[j] * inv_n;
  float rs = rsqrtf(fmaxf(sumsq[j] * inv_n - mu * mu, 0.f) + BN_EPS);
  float g = gamma[j] * rs, b = fmaf(-mu, g, beta[j]);
  float vmax = finv(gmax[j]);
  float vmin = finv(~gmin[j]);
  float v = fmaxf(fmaf(g, (g >= 0.f) ? vmax : vmin, b), 0.f);
  if (bf) ((__hip_bfloat16*)out)[j] = __float2bfloat16(v);
  else    ((float*)out)[j] = v;
}

extern "C" void kernel_launch(void* const* d_in, const int* in_sizes, int n_in,
                              void* d_out, int out_size, void* d_ws, size_t ws_size,
                              hipStream_t stream) {
  const void* x  = d_in[0];
  const void* ei = d_in[1];
  const int n_nodes = in_sizes[0] / IN_DIM;
  const int n_edges = in_sizes[1] / 2;
  const int nb = (n_nodes + 255) / 256;
  const int Mpad = (n_nodes + 127) & ~127;

  float* ws = (float*)d_ws;
  size_t off = 0;
  auto alloc = [&](size_t n) {
    float* p = ws + off;
    off += (n + 1023) & ~(size_t)1023;
    return p;
  };
  __hip_bfloat16* Wpk1 = (__hip_bfloat16*)alloc(384 * 256 / 2);
  __hip_bfloat16* Wpk2 = (__hip_bfloat16*)alloc(768 * 256 / 2);
  float* b1      = alloc(256);
  float* b2      = alloc(256);
  float* gamma1  = alloc(256);
  float* beta1   = alloc(256);
  float* gamma2  = alloc(256);
  float* beta2   = alloc(256);
  float* zeros   = alloc(2 * (size_t)n_nodes + 2048);
  int*   degf    = (int*)zeros;
  int*   degb    = degf + n_nodes;
  float* sum1    = zeros + 2 * (size_t)n_nodes;
  float* sumsq1  = sum1 + 256;
  float* sum2    = sum1 + 512;
  float* sumsq2  = sum1 + 768;
  unsigned* max2 = (unsigned*)(sum1 + 1024);
  unsigned* min2 = (unsigned*)(sum1 + 1280);
  int*   offf    = (int*)alloc(n_nodes + 1);
  int*   offb    = (int*)alloc(n_nodes + 1);
  int*   rankf   = (int*)alloc(n_edges);
  int*   rankb   = (int*)alloc(n_edges);
  int*   adjf    = (int*)alloc(n_edges);
  int*   adjb    = (int*)alloc(n_edges);
  int*   partials = (int*)alloc(2 * nb);
  unsigned char* X8 = (unsigned char*)alloc((size_t)n_nodes * 32);  // [n][128] fp8 of x
  __hip_bfloat16* A1 = (__hip_bfloat16*)alloc((size_t)Mpad * 384 / 2);
  __hip_bfloat16* A2 = (__hip_bfloat16*)alloc((size_t)Mpad * 768 / 2);
  // fp8 shadow of h for the layer-2 gather. Aliases A1 (dead after gemm1).
  unsigned char* A2q = (unsigned char*)A1;
  (void)ws_size; (void)n_in;

  hipMemsetAsync(zeros, 0, (2 * (size_t)n_nodes + 2048) * 4, stream);

  const int pgrid = (n_edges + 255) / 256;
  prep_kernel<<<pgrid, 256, 0, stream>>>(
      x, ei,
      d_in[2], d_in[3], d_in[4], d_in[5], d_in[6], d_in[7],
      d_in[8], d_in[9], d_in[10], d_in[11], d_in[12], d_in[13],
      d_in[14], d_in[15], d_in[16], d_in[17],
      degf, degb, rankf, rankb, A1, X8,
      Wpk1, b1, Wpk2, b2, gamma1, beta1, gamma2, beta2, n_nodes, n_edges);

  scan_part_kernel<<<2 * nb, 256, 0, stream>>>(degf, degb, offf, offb, partials, n_nodes, nb);
  scan_add_kernel<<<2 * nb, 256, 0, stream>>>(offf, offb, partials, n_nodes, nb, n_edges);
  fill_adj_kernel<<<(n_edges + 255) / 256, 256, 0, stream>>>(
      ei, rankf, rankb, offf, offb, adjf, adjb, n_edges);

  const float inv_n = 1.0f / (float)n_nodes;
  const int ggrid = (2 * n_nodes + 3) / 4;

  // ---- layer 1 (fp8-source gather, M128 GEMM) ----
  gather_mean_x8_kernel<<<ggrid, 256, 0, stream>>>(
      X8, A1, adjf, offf, adjb, offb, n_nodes);
  gemm_mfma128_kernel<384, true><<<Mpad / 128, 256, 0, stream>>>(
      A1, Wpk1, b1, A2, sum1, sumsq1, max2, min2, n_nodes);
  bn_apply_kernel<<<(n_nodes + 3) / 4, 256, 0, stream>>>(
      A2, A2q, sum1, sumsq1, gamma1, beta1, n_nodes, inv_n);

  // ---- layer 2 (fp8-source gather, single-barrier M32 GEMM) ----
  gather_mean_q8_kernel<<<ggrid, 256, 0, stream>>>(
      A2q, A2, adjf, offf, adjb, offb, n_nodes);
  gemm_mfma32_kernel<768, false><<<Mpad / 32, 256, 0, stream>>>(
      A2, Wpk2, b2, nullptr, sum2, sumsq2, max2, min2, n_nodes);
  finalize_kernel<<<1, 256, 0, stream>>>(
      (const unsigned*)x, sum2, sumsq2, max2, min2, gamma2, beta2, inv_n, d_out, out_size);
}

// Round 10
// 331.404 us; speedup vs baseline: 1.0975x; 1.0975x over previous
//
#include <hip/hip_runtime.h>
#include <hip/hip_bf16.h>

#define IN_DIM 128
#define HID 256
#define BN_EPS 1e-5f

typedef __attribute__((ext_vector_type(8))) short bf16x8;
typedef __attribute__((ext_vector_type(16))) float f32x16;
typedef __attribute__((ext_vector_type(2))) float f32x2;

// ---------- helpers ----------
__device__ __forceinline__ float ld_f(const void* p, size_t i, int bf16) {
  if (bf16) return __bfloat162float(((const __hip_bfloat16*)p)[i]);
  return ((const float*)p)[i];
}
__device__ __forceinline__ float blo(unsigned u) { return __uint_as_float(u << 16); }
__device__ __forceinline__ float bhi(unsigned u) { return __uint_as_float(u & 0xffff0000u); }
__device__ __forceinline__ unsigned short f2bf(float f) {
  __hip_bfloat16 b = __float2bfloat16(f);
  return __builtin_bit_cast(unsigned short, b);
}
__device__ __forceinline__ void load_lds16(const void* g, void* l) {
  __builtin_amdgcn_global_load_lds((const __attribute__((address_space(1))) void*)g,
                                   (__attribute__((address_space(3))) void*)l, 16, 0, 0);
}
// order-preserving float->uint key (monotone increasing); init 0 is neutral for max
__device__ __forceinline__ unsigned fkey(float v) {
  unsigned s = __float_as_uint(v);
  return (s & 0x80000000u) ? ~s : (s | 0x80000000u);
}
__device__ __forceinline__ float finv(unsigned k) {
  unsigned s = (k & 0x80000000u) ? (k ^ 0x80000000u) : ~k;
  return __uint_as_float(s);
}

// ---------- mega prep: flag detect + histogram (stores per-edge rank!) + x->A1/X8 + W packs ----------
__global__ void prep_kernel(
    const void* __restrict__ x, const void* __restrict__ ei,
    const void* Wl_f1, const void* bl_f1, const void* Wr_f1,
    const void* Wl_b1, const void* bl_b1, const void* Wr_b1,
    const void* Wl_f2, const void* bl_f2, const void* Wr_f2,
    const void* Wl_b2, const void* bl_b2, const void* Wr_b2,
    const void* g1, const void* be1, const void* g2, const void* be2,
    int* __restrict__ degf, int* __restrict__ degb,
    int* __restrict__ rankf, int* __restrict__ rankb,
    __hip_bfloat16* __restrict__ A1,
    unsigned char* __restrict__ X8,
    __hip_bfloat16* __restrict__ Wpk1, float* __restrict__ b1,
    __hip_bfloat16* __restrict__ Wpk2, float* __restrict__ b2,
    float* __restrict__ gamma1, float* __restrict__ beta1,
    float* __restrict__ gamma2, float* __restrict__ beta2,
    int n_nodes, int n_edges) {
  __shared__ int votes, nz;
  if (threadIdx.x == 0) { votes = 0; nz = 0; }
  __syncthreads();
  {
    unsigned e = (((const unsigned*)x)[threadIdx.x] >> 7) & 0xFFu;
    if (e >= 100u && e <= 140u) atomicAdd(&votes, 1);
    if (((const unsigned*)ei)[2 * threadIdx.x + 1] != 0u) atomicAdd(&nz, 1);
  }
  __syncthreads();
  const int bf = (votes > 128) ? 1 : 0;
  const int i32 = (nz > 0) ? 1 : 0;
  const int tid = blockIdx.x * 256 + threadIdx.x;
  const int nt = gridDim.x * 256;
  for (int i = tid; i < n_edges; i += nt) {
    int s, d;
    if (i32) { s = ((const int*)ei)[i]; d = ((const int*)ei)[n_edges + i]; }
    else     { s = (int)((const long long*)ei)[i]; d = (int)((const long long*)ei)[n_edges + i]; }
    rankf[i] = atomicAdd(&degf[d], 1);
    rankb[i] = atomicAdd(&degb[s], 1);
  }
  // x -> bf16 self-slice of A1 (exact path through Wr) AND dense fp8 X8 (gather source)
  const size_t nq = (size_t)n_nodes * IN_DIM / 4;
  for (size_t q = tid; q < nq; q += nt) {
    const int row = (int)(q >> 5), j = (int)(q & 31) * 4;
    __hip_bfloat16* dstp = A1 + (size_t)row * 384 + 256 + j;
    float f0, f1, f2, f3;
    if (bf) {
      uint2 v = ((const uint2*)x)[q];
      *(uint2*)dstp = v;
      f0 = blo(v.x); f1 = bhi(v.x); f2 = blo(v.y); f3 = bhi(v.y);
    } else {
      float4 v = ((const float4*)x)[q];
      unsigned short o[4] = {f2bf(v.x), f2bf(v.y), f2bf(v.z), f2bf(v.w)};
      *(uint2*)dstp = *(uint2*)o;
      f0 = v.x; f1 = v.y; f2 = v.z; f3 = v.w;
    }
    int p8 = __builtin_amdgcn_cvt_pk_fp8_f32(f0, f1, 0, false);
    p8 = __builtin_amdgcn_cvt_pk_fp8_f32(f2, f3, p8, true);
    *(int*)(X8 + (size_t)row * 128 + j) = p8;
  }
  for (int idx = tid; idx < 768 * 256; idx += nt) {
    {
      int j = idx & 7, l = (idx >> 3) & 63, rest = idx >> 9;
      int s = rest % 48, t = rest / 48;
      int k = s * 16 + (l >> 5) * 8 + j, col = t * 32 + (l & 31);
      float v;
      if (k < 256)      v = ld_f(Wl_f2, (size_t)k * 256 + col, bf);
      else if (k < 512) v = ld_f(Wl_b2, (size_t)(k - 256) * 256 + col, bf);
      else              v = ld_f(Wr_f2, (size_t)(k - 512) * 256 + col, bf) +
                            ld_f(Wr_b2, (size_t)(k - 512) * 256 + col, bf);
      Wpk2[idx] = __float2bfloat16(v);
    }
    if (idx < 384 * 256) {
      int j = idx & 7, l = (idx >> 3) & 63, rest = idx >> 9;
      int s = rest % 24, t = rest / 24;
      int k = s * 16 + (l >> 5) * 8 + j, col = t * 32 + (l & 31);
      float v;
      if (k < 128)      v = ld_f(Wl_f1, (size_t)k * 256 + col, bf);
      else if (k < 256) v = ld_f(Wl_b1, (size_t)(k - 128) * 256 + col, bf);
      else              v = ld_f(Wr_f1, (size_t)(k - 256) * 256 + col, bf) +
                            ld_f(Wr_b1, (size_t)(k - 256) * 256 + col, bf);
      Wpk1[idx] = __float2bfloat16(v);
    }
    if (idx < 256) {
      b1[idx] = ld_f(bl_f1, idx, bf) + ld_f(bl_b1, idx, bf);
      b2[idx] = ld_f(bl_f2, idx, bf) + ld_f(bl_b2, idx, bf);
      gamma1[idx] = ld_f(g1, idx, bf);
      beta1[idx]  = ld_f(be1, idx, bf);
      gamma2[idx] = ld_f(g2, idx, bf);
      beta2[idx]  = ld_f(be2, idx, bf);
    }
  }
}

// ---------- CSR build ----------
__global__ void scan_part_kernel(const int* __restrict__ degf, const int* __restrict__ degb,
                                 int* __restrict__ offf, int* __restrict__ offb,
                                 int* __restrict__ partials, int n, int nb) {
  __shared__ int buf[256];
  const int b = blockIdx.x;
  const int* deg = (b < nb) ? degf : degb;
  int* off = (b < nb) ? offf : offb;
  const int chunk = (b < nb) ? b : (b - nb);
  const int i = chunk * 256 + threadIdx.x;
  int v = (i < n) ? deg[i] : 0;
  buf[threadIdx.x] = v;
  __syncthreads();
  for (int s = 1; s < 256; s <<= 1) {
    int t = (threadIdx.x >= s) ? buf[threadIdx.x - s] : 0;
    __syncthreads();
    buf[threadIdx.x] += t;
    __syncthreads();
  }
  if (i < n) off[i] = buf[threadIdx.x] - v;
  if (threadIdx.x == 255) partials[b] = buf[255];
}

__global__ void scan_add_kernel(int* __restrict__ offf, int* __restrict__ offb,
                                const int* __restrict__ partials, int n, int nb, int n_edges) {
  __shared__ int red[256];
  const int b = blockIdx.x;
  int* off = (b < nb) ? offf : offb;
  const int chunk = (b < nb) ? b : (b - nb);
  const int abase = (b < nb) ? 0 : nb;
  int v = (threadIdx.x < chunk) ? partials[abase + threadIdx.x] : 0;
  red[threadIdx.x] = v;
  __syncthreads();
  for (int s = 128; s > 0; s >>= 1) {
    if (threadIdx.x < s) red[threadIdx.x] += red[threadIdx.x + s];
    __syncthreads();
  }
  const int prefix = red[0];
  const int i = chunk * 256 + threadIdx.x;
  if (i < n) off[i] += prefix;
  if (b == 0 && threadIdx.x == 0) { offf[n] = n_edges; offb[n] = n_edges; }
}

// ---------- atomic-free edge placement ----------
__global__ void fill_adj_kernel(const void* __restrict__ ei,
                                const int* __restrict__ rankf, const int* __restrict__ rankb,
                                const int* __restrict__ offf, const int* __restrict__ offb,
                                int* __restrict__ adjf, int* __restrict__ adjb, int n_edges) {
  __shared__ int nz;
  if (threadIdx.x == 0) nz = 0;
  __syncthreads();
  if (((const unsigned*)ei)[2 * threadIdx.x + 1] != 0u) atomicAdd(&nz, 1);
  __syncthreads();
  const int i32 = nz > 0;
  int i = blockIdx.x * 256 + threadIdx.x;
  if (i >= n_edges) return;
  int s, d;
  if (i32) { s = ((const int*)ei)[i]; d = ((const int*)ei)[n_edges + i]; }
  else     { s = (int)((const long long*)ei)[i]; d = (int)((const long long*)ei)[n_edges + i]; }
  adjf[offf[d] + rankf[i]] = s;
  adjb[offb[s] + rankb[i]] = d;
}

// ---------- gather-mean fp8, layer 1: X8[n][128] -> bf16 mean slices of A1 ----------
__global__ __launch_bounds__(256) void gather_mean_x8_kernel(
    const unsigned char* __restrict__ Q,  // [n_nodes][128] fp8 e4m3
    __hip_bfloat16* __restrict__ A1,      // row stride 384
    const int* __restrict__ adjf, const int* __restrict__ offf,
    const int* __restrict__ adjb, const int* __restrict__ offb, int n_nodes) {
  const int gw = (int)(((size_t)blockIdx.x * 256 + threadIdx.x) >> 6);
  const int lane = threadIdx.x & 63;
  if (gw >= 2 * n_nodes) return;
  int node, dir;
  const int *adj, *off;
  if (gw < n_nodes) { node = gw;           adj = adjf; off = offf; dir = 0; }
  else              { node = gw - n_nodes; adj = adjb; off = offb; dir = 1; }
  const int s = off[node], e = off[node + 1];
  const int sub = lane >> 4, cl = lane & 15;  // 4 subs x 16 col-lanes (8 cols each)
  auto clampi = [&](int i) { return max(min(i, e - 1), 0); };
  auto ROW = [&](int a) { return *(const uint2*)(Q + (size_t)a * 128 + cl * 8); };
  float acc[8] = {0.f, 0.f, 0.f, 0.f, 0.f, 0.f, 0.f, 0.f};
  int i = s + sub;
  int a0 = adj[clampi(i)];
  int a1 = adj[clampi(i + 4)];
  int a2 = adj[clampi(i + 8)];
  int a3 = adj[clampi(i + 12)];
  uint2 r0 = ROW(a0);
  uint2 r1 = ROW(a1);
  for (; i < e; i += 8) {
    const uint2 r2 = ROW(a2), r3 = ROW(a3);  // next pair in flight
    const int a4 = adj[clampi(i + 16)];
    const int a5 = adj[clampi(i + 20)];
    {
      f32x2 p;
      p = __builtin_amdgcn_cvt_pk_f32_fp8((int)r0.x, false); acc[0] += p.x; acc[1] += p.y;
      p = __builtin_amdgcn_cvt_pk_f32_fp8((int)r0.x, true);  acc[2] += p.x; acc[3] += p.y;
      p = __builtin_amdgcn_cvt_pk_f32_fp8((int)r0.y, false); acc[4] += p.x; acc[5] += p.y;
      p = __builtin_amdgcn_cvt_pk_f32_fp8((int)r0.y, true);  acc[6] += p.x; acc[7] += p.y;
    }
    if (i + 4 < e) {
      f32x2 p;
      p = __builtin_amdgcn_cvt_pk_f32_fp8((int)r1.x, false); acc[0] += p.x; acc[1] += p.y;
      p = __builtin_amdgcn_cvt_pk_f32_fp8((int)r1.x, true);  acc[2] += p.x; acc[3] += p.y;
      p = __builtin_amdgcn_cvt_pk_f32_fp8((int)r1.y, false); acc[4] += p.x; acc[5] += p.y;
      p = __builtin_amdgcn_cvt_pk_f32_fp8((int)r1.y, true);  acc[6] += p.x; acc[7] += p.y;
    }
    r0 = r2; r1 = r3; a2 = a4; a3 = a5;
  }
#pragma unroll
  for (int o = 32; o >= 16; o >>= 1) {
#pragma unroll
    for (int k = 0; k < 8; ++k) acc[k] += __shfl_xor(acc[k], o, 64);
  }
  if (sub == 0) {
    const float inv = 1.0f / (float)max(e - s, 1);
    union { unsigned short us[8]; uint4 v; } o;
#pragma unroll
    for (int k = 0; k < 8; ++k) o.us[k] = f2bf(acc[k] * inv);
    *(uint4*)(A1 + (size_t)node * 384 + dir * 128 + cl * 8) = o.v;
  }
}

// ---------- gather-mean fp8, layer 2 (r5-measured; unchanged) ----------
__global__ __launch_bounds__(256) void gather_mean_q8_kernel(
    const unsigned char* __restrict__ Q,  // [n_nodes][256] fp8 e4m3
    __hip_bfloat16* __restrict__ A,       // A2, row stride 768
    const int* __restrict__ adjf, const int* __restrict__ offf,
    const int* __restrict__ adjb, const int* __restrict__ offb, int n_nodes) {
  const int gw = (int)(((size_t)blockIdx.x * 256 + threadIdx.x) >> 6);
  const int lane = threadIdx.x & 63;
  if (gw >= 2 * n_nodes) return;
  int node, dir;
  const int *adj, *off;
  if (gw < n_nodes) { node = gw;           adj = adjf; off = offf; dir = 0; }
  else              { node = gw - n_nodes; adj = adjb; off = offb; dir = 1; }
  const int s = off[node], e = off[node + 1];
  const int sub = lane >> 5, cl = lane & 31;
  auto clampi = [&](int i) { return max(min(i, e - 1), 0); };
  auto ROW = [&](int a) { return *(const uint2*)(Q + (size_t)a * 256 + cl * 8); };
  float acc[8] = {0.f, 0.f, 0.f, 0.f, 0.f, 0.f, 0.f, 0.f};
  int i = s + sub;
  int a0 = adj[clampi(i)];
  int a1 = adj[clampi(i + 2)];
  int a2 = adj[clampi(i + 4)];
  int a3 = adj[clampi(i + 6)];
  uint2 r0 = ROW(a0);
  uint2 r1 = ROW(a1);
  for (; i < e; i += 4) {
    const uint2 r2 = ROW(a2), r3 = ROW(a3);
    const int a4 = adj[clampi(i + 8)];
    const int a5 = adj[clampi(i + 10)];
    {
      f32x2 p;
      p = __builtin_amdgcn_cvt_pk_f32_fp8((int)r0.x, false); acc[0] += p.x; acc[1] += p.y;
      p = __builtin_amdgcn_cvt_pk_f32_fp8((int)r0.x, true);  acc[2] += p.x; acc[3] += p.y;
      p = __builtin_amdgcn_cvt_pk_f32_fp8((int)r0.y, false); acc[4] += p.x; acc[5] += p.y;
      p = __builtin_amdgcn_cvt_pk_f32_fp8((int)r0.y, true);  acc[6] += p.x; acc[7] += p.y;
    }
    if (i + 2 < e) {
      f32x2 p;
      p = __builtin_amdgcn_cvt_pk_f32_fp8((int)r1.x, false); acc[0] += p.x; acc[1] += p.y;
      p = __builtin_amdgcn_cvt_pk_f32_fp8((int)r1.x, true);  acc[2] += p.x; acc[3] += p.y;
      p = __builtin_amdgcn_cvt_pk_f32_fp8((int)r1.y, false); acc[4] += p.x; acc[5] += p.y;
      p = __builtin_amdgcn_cvt_pk_f32_fp8((int)r1.y, true);  acc[6] += p.x; acc[7] += p.y;
    }
    r0 = r2; r1 = r3; a2 = a4; a3 = a5;
  }
#pragma unroll
  for (int k = 0; k < 8; ++k) acc[k] += __shfl_xor(acc[k], 32, 64);
  if (sub == 0) {
    const float inv = 1.0f / (float)max(e - s, 1);
    union { unsigned short us[8]; uint4 v; } o;
#pragma unroll
    for (int k = 0; k < 8; ++k) o.us[k] = f2bf(acc[k] * inv);
    *(uint4*)(A + (size_t)node * 768 + dir * 256 + cl * 8) = o.v;
  }
}

// ---------- MFMA GEMM, M128 tile (r5 measured-best for layer 1; unchanged) ----------
template <int K, bool STORE>
__global__ __launch_bounds__(256, 2) void gemm_mfma128_kernel(
    const __hip_bfloat16* __restrict__ A, const __hip_bfloat16* __restrict__ Wpk,
    const float* __restrict__ bias, __hip_bfloat16* __restrict__ Cb,
    float* __restrict__ bnsum, float* __restrict__ bnsum2,
    unsigned* __restrict__ gmax, unsigned* __restrict__ gmin, int M) {
  constexpr int S = K / 16;
  constexpr int NIT = K / 128;
  __shared__ __align__(16) union SMem {
    char at[2][32768];
    struct { float colsum[256], colsum2[256]; unsigned cmax[256], cmin[256]; } st;
  } sm;
  const int wave = threadIdx.x >> 6, lane = threadIdx.x & 63;
  const int rw = wave >> 1, cw = wave & 1;
  const int rbase = blockIdx.x * 128;
  const char* gsrc = (const char*)(A + (size_t)(rbase + wave * 32 + (lane & 31)) * K)
                   + (lane >> 5) * 16;
  char* lb[2] = { &sm.at[0][wave * 1024], &sm.at[1][wave * 1024] };

  {
#pragma unroll
    for (int d = 0; d < 8; ++d) load_lds16(gsrc + d * 32, lb[0] + d * 4096);
  }

  const __hip_bfloat16* wbase = Wpk + ((size_t)(cw * 4) * S * 64 + lane) * 8;
  f32x16 acc[2][4] = {};

  for (int kb = 0; kb < NIT; ++kb) {
    __syncthreads();
    if (kb + 1 < NIT) {
      const char* g = gsrc + (size_t)(kb + 1) * 256;
      char* l = lb[(kb + 1) & 1];
#pragma unroll
      for (int d = 0; d < 8; ++d) load_lds16(g + d * 32, l + d * 4096);
    }
    const char* ab = sm.at[kb & 1];
#pragma unroll
    for (int s = 0; s < 8; ++s) {
      const int ks = kb * 8 + s;
      const bf16x8 a0 = *(const bf16x8*)(ab + (s * 4 + rw * 2 + 0) * 1024 + lane * 16);
      const bf16x8 a1 = *(const bf16x8*)(ab + (s * 4 + rw * 2 + 1) * 1024 + lane * 16);
      const bf16x8 w0 = *(const bf16x8*)(wbase + ((size_t)0 * S + ks) * 512);
      const bf16x8 w1 = *(const bf16x8*)(wbase + ((size_t)1 * S + ks) * 512);
      const bf16x8 w2 = *(const bf16x8*)(wbase + ((size_t)2 * S + ks) * 512);
      const bf16x8 w3 = *(const bf16x8*)(wbase + ((size_t)3 * S + ks) * 512);
      acc[0][0] = __builtin_amdgcn_mfma_f32_32x32x16_bf16(a0, w0, acc[0][0], 0, 0, 0);
      acc[0][1] = __builtin_amdgcn_mfma_f32_32x32x16_bf16(a0, w1, acc[0][1], 0, 0, 0);
      acc[0][2] = __builtin_amdgcn_mfma_f32_32x32x16_bf16(a0, w2, acc[0][2], 0, 0, 0);
      acc[0][3] = __builtin_amdgcn_mfma_f32_32x32x16_bf16(a0, w3, acc[0][3], 0, 0, 0);
      acc[1][0] = __builtin_amdgcn_mfma_f32_32x32x16_bf16(a1, w0, acc[1][0], 0, 0, 0);
      acc[1][1] = __builtin_amdgcn_mfma_f32_32x32x16_bf16(a1, w1, acc[1][1], 0, 0, 0);
      acc[1][2] = __builtin_amdgcn_mfma_f32_32x32x16_bf16(a1, w2, acc[1][2], 0, 0, 0);
      acc[1][3] = __builtin_amdgcn_mfma_f32_32x32x16_bf16(a1, w3, acc[1][3], 0, 0, 0);
    }
  }

  __syncthreads();
  sm.st.colsum[threadIdx.x] = 0.f;
  sm.st.colsum2[threadIdx.x] = 0.f;
  if (!STORE) { sm.st.cmax[threadIdx.x] = 0u; sm.st.cmin[threadIdx.x] = 0u; }
  __syncthreads();

#pragma unroll
  for (int rh = 0; rh < 2; ++rh) {
#pragma unroll
    for (int t = 0; t < 4; ++t) {
      const int col = cw * 128 + t * 32 + (lane & 31);
      const float bj = bias[col];
      float ls = 0.f, ls2 = 0.f, lmax = -INFINITY, lmin = INFINITY;
#pragma unroll
      for (int r = 0; r < 16; ++r) {
        const int row = rbase + rw * 64 + rh * 32 + (r & 3) + 8 * (r >> 2) + 4 * (lane >> 5);
        if (row < M) {
          float v = acc[rh][t][r] + bj;
          if (STORE) Cb[(size_t)row * 768 + 512 + col] = __float2bfloat16(v);
          ls += v;
          ls2 = fmaf(v, v, ls2);
          if (!STORE) { lmax = fmaxf(lmax, v); lmin = fminf(lmin, v); }
        }
      }
      atomicAdd(&sm.st.colsum[col], ls);
      atomicAdd(&sm.st.colsum2[col], ls2);
      if (!STORE) {
        atomicMax(&sm.st.cmax[col], fkey(lmax));
        atomicMax(&sm.st.cmin[col], ~fkey(lmin));
      }
    }
  }
  __syncthreads();
  atomicAdd(&bnsum[threadIdx.x], sm.st.colsum[threadIdx.x]);
  atomicAdd(&bnsum2[threadIdx.x], sm.st.colsum2[threadIdx.x]);
  if (!STORE) {
    atomicMax(&gmax[threadIdx.x], sm.st.cmax[threadIdx.x]);
    atomicMax(&gmin[threadIdx.x], sm.st.cmin[threadIdx.x]);
  }
}

// ---------- MFMA GEMM, persistent W-in-registers (layer 2, no C store) ----------
// r5-r9 synthesis: every gemm2 variant was latency-bound on per-k-step W loads from L2
// (barriers drain them; compiler won't pipeline them). Fix: each wave owns ONE 32-col
// tile, whose full-K W is 48 x bf16x8 = 192 VGPR -> hoist into registers ONCE. Block is
// persistent over m-tiles (grid = 2 col-groups x NBS) so the one-time W read amortizes.
// Inner loop barriers now drain only the A-staging DMAs; W is immune. All wr[] indices
// are compile-time (NIT and s loops fully unrolled) per rule #20.
template <int K, int NBS>
__global__ __launch_bounds__(256, 2) void gemm_persist_kernel(
    const __hip_bfloat16* __restrict__ A, const __hip_bfloat16* __restrict__ Wpk,
    const float* __restrict__ bias,
    float* __restrict__ bnsum, float* __restrict__ bnsum2,
    unsigned* __restrict__ gmax, unsigned* __restrict__ gmin, int M, int ntiles) {
  constexpr int S = K / 16;    // 48 k-steps
  constexpr int NIT = K / 128; // 6 BK iterations
  __shared__ __align__(16) union SMem {
    char at[2][16384];  // 64 rows x BK=128 x 2B double buffer
    struct { float colsum[256], colsum2[256]; unsigned cmax[256], cmin[256]; } st;
  } sm;
  const int wave = threadIdx.x >> 6, lane = threadIdx.x & 63;
  const int cg = (int)(blockIdx.x & 1);       // col-group: cols [cg*128, cg*128+128)
  const int bstart = (int)(blockIdx.x >> 1);  // first m-tile
  const int ct = cg * 4 + wave;               // this wave's 32-col tile

  // hoist this wave's full-K W into registers (192 VGPR), once per block
  bf16x8 wr[S];
#pragma unroll
  for (int d = 0; d < S; ++d)
    wr[d] = *(const bf16x8*)(Wpk + ((size_t)ct * S + d) * 512 + lane * 8);

  const int col = ct * 32 + (lane & 31);
  const float bj = bias[col];
  float ls = 0.f, ls2 = 0.f, lmax = -INFINITY, lmin = INFINITY;
  const size_t rh_off = (size_t)64 * K;  // 32 rows * K * 2B (byte offset)

  for (int m = bstart; m < ntiles; m += NBS) {
    const int rbase = m * 64;
    const char* gsrc = (const char*)(A + (size_t)(rbase + (lane & 31)) * K) + (lane >> 5) * 16;
    auto STAGE = [&](int kb, int buf) {
#pragma unroll
      for (int ss = 0; ss < 2; ++ss) {
        const int s = wave * 2 + ss;
        const char* g = gsrc + (size_t)kb * 256 + s * 32;
        load_lds16(g,          &sm.at[buf][(s * 2 + 0) * 1024]);
        load_lds16(g + rh_off, &sm.at[buf][(s * 2 + 1) * 1024]);
      }
    };
    STAGE(0, 0);
    f32x16 acc[2] = {};
#pragma unroll
    for (int kb = 0; kb < NIT; ++kb) {
      __syncthreads();  // drains A-staging DMAs only; W lives in registers
      if (kb + 1 < NIT) STAGE(kb + 1, (kb + 1) & 1);
      const char* ab = sm.at[kb & 1];
#pragma unroll
      for (int s = 0; s < 8; ++s) {
        const bf16x8 a0 = *(const bf16x8*)(ab + (s * 2 + 0) * 1024 + lane * 16);
        const bf16x8 a1 = *(const bf16x8*)(ab + (s * 2 + 1) * 1024 + lane * 16);
        const bf16x8 w = wr[kb * 8 + s];  // compile-time index
        acc[0] = __builtin_amdgcn_mfma_f32_32x32x16_bf16(a0, w, acc[0], 0, 0, 0);
        acc[1] = __builtin_amdgcn_mfma_f32_32x32x16_bf16(a1, w, acc[1], 0, 0, 0);
      }
    }
    // fold this tile's acc into running per-column stats (no C store for layer 2)
#pragma unroll
    for (int rh = 0; rh < 2; ++rh) {
#pragma unroll
      for (int r = 0; r < 16; ++r) {
        const int row = rbase + rh * 32 + (r & 3) + 8 * (r >> 2) + 4 * (lane >> 5);
        if (row < M) {
          float v = acc[rh][r] + bj;
          ls += v;
          ls2 = fmaf(v, v, ls2);
          lmax = fmaxf(lmax, v);
          lmin = fminf(lmin, v);
        }
      }
    }
    __syncthreads();  // all waves done reading this tile's LDS before next STAGE(0,0)
  }

  // single stats epilogue (LDS aliased after final barrier above)
  sm.st.colsum[threadIdx.x] = 0.f;
  sm.st.colsum2[threadIdx.x] = 0.f;
  sm.st.cmax[threadIdx.x] = 0u;
  sm.st.cmin[threadIdx.x] = 0u;
  __syncthreads();
  atomicAdd(&sm.st.colsum[col], ls);
  atomicAdd(&sm.st.colsum2[col], ls2);
  atomicMax(&sm.st.cmax[col], fkey(lmax));
  atomicMax(&sm.st.cmin[col], ~fkey(lmin));
  __syncthreads();
  atomicAdd(&bnsum[threadIdx.x], sm.st.colsum[threadIdx.x]);
  atomicAdd(&bnsum2[threadIdx.x], sm.st.colsum2[threadIdx.x]);
  atomicMax(&gmax[threadIdx.x], sm.st.cmax[threadIdx.x]);
  atomicMax(&gmin[threadIdx.x], sm.st.cmin[threadIdx.x]);
}

// ---------- BN+ReLU in place on A2 self-slice + fp8 shadow for the layer-2 gather ----------
__global__ void bn_apply_kernel(__hip_bfloat16* __restrict__ A2,
                                unsigned char* __restrict__ A2q,
                                const float* __restrict__ sum, const float* __restrict__ sumsq,
                                const float* __restrict__ gamma, const float* __restrict__ beta,
                                int n_nodes, float inv_n) {
  const int j0 = (threadIdx.x & 63) * 4;
  const int row = blockIdx.x * 4 + (threadIdx.x >> 6);
  if (row >= n_nodes) return;
  float g[4], b[4];
#pragma unroll
  for (int k = 0; k < 4; ++k) {
    const int j = j0 + k;
    float mu = sum[j] * inv_n;
    float rs = rsqrtf(fmaxf(sumsq[j] * inv_n - mu * mu, 0.f) + BN_EPS);
    g[k] = gamma[j] * rs;
    b[k] = fmaf(-mu, g[k], beta[j]);
  }
  uint2* p = (uint2*)(A2 + (size_t)row * 768 + 512 + j0);
  uint2 w = *p;
  float h[4];
  h[0] = fmaxf(fmaf(blo(w.x), g[0], b[0]), 0.f);
  h[1] = fmaxf(fmaf(bhi(w.x), g[1], b[1]), 0.f);
  h[2] = fmaxf(fmaf(blo(w.y), g[2], b[2]), 0.f);
  h[3] = fmaxf(fmaf(bhi(w.y), g[3], b[3]), 0.f);
  unsigned short us[4] = {f2bf(h[0]), f2bf(h[1]), f2bf(h[2]), f2bf(h[3])};
  *p = *(uint2*)us;
  int q8 = __builtin_amdgcn_cvt_pk_fp8_f32(h[0], h[1], 0, false);
  q8 = __builtin_amdgcn_cvt_pk_fp8_f32(h[2], h[3], q8, true);
  *(int*)(A2q + (size_t)row * 256 + j0) = q8;
}

// ---------- finalize ----------
__global__ void finalize_kernel(const unsigned* __restrict__ xw,
                                const float* __restrict__ sum, const float* __restrict__ sumsq,
                                const unsigned* __restrict__ gmax, const unsigned* __restrict__ gmin,
                                const float* __restrict__ gamma, const float* __restrict__ beta,
                                float inv_n, void* __restrict__ out, int out_size) {
  __shared__ int votes;
  if (threadIdx.x == 0) votes = 0;
  __syncthreads();
  unsigned e = (xw[threadIdx.x] >> 7) & 0xFFu;
  if (e >= 100u && e <= 140u) atomicAdd(&votes, 1);
  __syncthreads();
  int bf = votes > 128;
  int j = threadIdx.x;
  if (j >= out_size) return;
  float mu = sum[j] * inv_n;
  float rs = rsqrtf(fmaxf(sumsq[j] * inv_n - mu * mu, 0.f) + BN_EPS);
  float g = gamma[j] * rs, b = fmaf(-mu, g, beta[j]);
  float vmax = finv(gmax[j]);
  float vmin = finv(~gmin[j]);
  float v = fmaxf(fmaf(g, (g >= 0.f) ? vmax : vmin, b), 0.f);
  if (bf) ((__hip_bfloat16*)out)[j] = __float2bfloat16(v);
  else    ((float*)out)[j] = v;
}

extern "C" void kernel_launch(void* const* d_in, const int* in_sizes, int n_in,
                              void* d_out, int out_size, void* d_ws, size_t ws_size,
                              hipStream_t stream) {
  const void* x  = d_in[0];
  const void* ei = d_in[1];
  const int n_nodes = in_sizes[0] / IN_DIM;
  const int n_edges = in_sizes[1] / 2;
  const int nb = (n_nodes + 255) / 256;
  const int Mpad = (n_nodes + 127) & ~127;

  float* ws = (float*)d_ws;
  size_t off = 0;
  auto alloc = [&](size_t n) {
    float* p = ws + off;
    off += (n + 1023) & ~(size_t)1023;
    return p;
  };
  __hip_bfloat16* Wpk1 = (__hip_bfloat16*)alloc(384 * 256 / 2);
  __hip_bfloat16* Wpk2 = (__hip_bfloat16*)alloc(768 * 256 / 2);
  float* b1      = alloc(256);
  float* b2      = alloc(256);
  float* gamma1  = alloc(256);
  float* beta1   = alloc(256);
  float* gamma2  = alloc(256);
  float* beta2   = alloc(256);
  float* zeros   = alloc(2 * (size_t)n_nodes + 2048);
  int*   degf    = (int*)zeros;
  int*   degb    = degf + n_nodes;
  float* sum1    = zeros + 2 * (size_t)n_nodes;
  float* sumsq1  = sum1 + 256;
  float* sum2    = sum1 + 512;
  float* sumsq2  = sum1 + 768;
  unsigned* max2 = (unsigned*)(sum1 + 1024);
  unsigned* min2 = (unsigned*)(sum1 + 1280);
  int*   offf    = (int*)alloc(n_nodes + 1);
  int*   offb    = (int*)alloc(n_nodes + 1);
  int*   rankf   = (int*)alloc(n_edges);
  int*   rankb   = (int*)alloc(n_edges);
  int*   adjf    = (int*)alloc(n_edges);
  int*   adjb    = (int*)alloc(n_edges);
  int*   partials = (int*)alloc(2 * nb);
  unsigned char* X8 = (unsigned char*)alloc((size_t)n_nodes * 32);  // [n][128] fp8 of x
  __hip_bfloat16* A1 = (__hip_bfloat16*)alloc((size_t)Mpad * 384 / 2);
  __hip_bfloat16* A2 = (__hip_bfloat16*)alloc((size_t)Mpad * 768 / 2);
  // fp8 shadow of h for the layer-2 gather. Aliases A1 (dead after gemm1).
  unsigned char* A2q = (unsigned char*)A1;
  (void)ws_size; (void)n_in;

  hipMemsetAsync(zeros, 0, (2 * (size_t)n_nodes + 2048) * 4, stream);

  const int pgrid = (n_edges + 255) / 256;
  prep_kernel<<<pgrid, 256, 0, stream>>>(
      x, ei,
      d_in[2], d_in[3], d_in[4], d_in[5], d_in[6], d_in[7],
      d_in[8], d_in[9], d_in[10], d_in[11], d_in[12], d_in[13],
      d_in[14], d_in[15], d_in[16], d_in[17],
      degf, degb, rankf, rankb, A1, X8,
      Wpk1, b1, Wpk2, b2, gamma1, beta1, gamma2, beta2, n_nodes, n_edges);

  scan_part_kernel<<<2 * nb, 256, 0, stream>>>(degf, degb, offf, offb, partials, n_nodes, nb);
  scan_add_kernel<<<2 * nb, 256, 0, stream>>>(offf, offb, partials, n_nodes, nb, n_edges);
  fill_adj_kernel<<<(n_edges + 255) / 256, 256, 0, stream>>>(
      ei, rankf, rankb, offf, offb, adjf, adjb, n_edges);

  const float inv_n = 1.0f / (float)n_nodes;
  const int ggrid = (2 * n_nodes + 3) / 4;

  // ---- layer 1 (fp8-source gather, M128 GEMM) ----
  gather_mean_x8_kernel<<<ggrid, 256, 0, stream>>>(
      X8, A1, adjf, offf, adjb, offb, n_nodes);
  gemm_mfma128_kernel<384, true><<<Mpad / 128, 256, 0, stream>>>(
      A1, Wpk1, b1, A2, sum1, sumsq1, max2, min2, n_nodes);
  bn_apply_kernel<<<(n_nodes + 3) / 4, 256, 0, stream>>>(
      A2, A2q, sum1, sumsq1, gamma1, beta1, n_nodes, inv_n);

  // ---- layer 2 (fp8-source gather, persistent W-in-registers GEMM) ----
  gather_mean_q8_kernel<<<ggrid, 256, 0, stream>>>(
      A2q, A2, adjf, offf, adjb, offb, n_nodes);
  gemm_persist_kernel<768, 256><<<2 * 256, 256, 0, stream>>>(
      A2, Wpk2, b2, sum2, sumsq2, max2, min2, n_nodes, Mpad / 64);
  finalize_kernel<<<1, 256, 0, stream>>>(
      (const unsigned*)x, sum2, sumsq2, max2, min2, gamma2, beta2, inv_n, d_out, out_size);
}

// Round 11
// 323.913 us; speedup vs baseline: 1.1229x; 1.0231x over previous
//
#include <hip/hip_runtime.h>
#include <hip/hip_bf16.h>

#define IN_DIM 128
#define HID 256
#define BN_EPS 1e-5f

typedef __attribute__((ext_vector_type(8))) short bf16x8;
typedef __attribute__((ext_vector_type(16))) float f32x16;
typedef __attribute__((ext_vector_type(2))) float f32x2;

// ---------- helpers ----------
__device__ __forceinline__ float ld_f(const void* p, size_t i, int bf16) {
  if (bf16) return __bfloat162float(((const __hip_bfloat16*)p)[i]);
  return ((const float*)p)[i];
}
__device__ __forceinline__ float blo(unsigned u) { return __uint_as_float(u << 16); }
__device__ __forceinline__ float bhi(unsigned u) { return __uint_as_float(u & 0xffff0000u); }
__device__ __forceinline__ unsigned short f2bf(float f) {
  __hip_bfloat16 b = __float2bfloat16(f);
  return __builtin_bit_cast(unsigned short, b);
}
__device__ __forceinline__ void load_lds16(const void* g, void* l) {
  __builtin_amdgcn_global_load_lds((const __attribute__((address_space(1))) void*)g,
                                   (__attribute__((address_space(3))) void*)l, 16, 0, 0);
}
// order-preserving float->uint key (monotone increasing); init 0 is neutral for max
__device__ __forceinline__ unsigned fkey(float v) {
  unsigned s = __float_as_uint(v);
  return (s & 0x80000000u) ? ~s : (s | 0x80000000u);
}
__device__ __forceinline__ float finv(unsigned k) {
  unsigned s = (k & 0x80000000u) ? (k ^ 0x80000000u) : ~k;
  return __uint_as_float(s);
}

// ---------- mega prep: flag detect + histogram (stores per-edge rank!) + x->A1/X8 + W packs ----------
__global__ void prep_kernel(
    const void* __restrict__ x, const void* __restrict__ ei,
    const void* Wl_f1, const void* bl_f1, const void* Wr_f1,
    const void* Wl_b1, const void* bl_b1, const void* Wr_b1,
    const void* Wl_f2, const void* bl_f2, const void* Wr_f2,
    const void* Wl_b2, const void* bl_b2, const void* Wr_b2,
    const void* g1, const void* be1, const void* g2, const void* be2,
    int* __restrict__ degf, int* __restrict__ degb,
    int* __restrict__ rankf, int* __restrict__ rankb,
    __hip_bfloat16* __restrict__ A1,
    unsigned char* __restrict__ X8,
    __hip_bfloat16* __restrict__ Wpk1, float* __restrict__ b1,
    __hip_bfloat16* __restrict__ Wpk2, float* __restrict__ b2,
    float* __restrict__ gamma1, float* __restrict__ beta1,
    float* __restrict__ gamma2, float* __restrict__ beta2,
    int n_nodes, int n_edges) {
  __shared__ int votes, nz;
  if (threadIdx.x == 0) { votes = 0; nz = 0; }
  __syncthreads();
  {
    unsigned e = (((const unsigned*)x)[threadIdx.x] >> 7) & 0xFFu;
    if (e >= 100u && e <= 140u) atomicAdd(&votes, 1);
    if (((const unsigned*)ei)[2 * threadIdx.x + 1] != 0u) atomicAdd(&nz, 1);
  }
  __syncthreads();
  const int bf = (votes > 128) ? 1 : 0;
  const int i32 = (nz > 0) ? 1 : 0;
  const int tid = blockIdx.x * 256 + threadIdx.x;
  const int nt = gridDim.x * 256;
  for (int i = tid; i < n_edges; i += nt) {
    int s, d;
    if (i32) { s = ((const int*)ei)[i]; d = ((const int*)ei)[n_edges + i]; }
    else     { s = (int)((const long long*)ei)[i]; d = (int)((const long long*)ei)[n_edges + i]; }
    rankf[i] = atomicAdd(&degf[d], 1);
    rankb[i] = atomicAdd(&degb[s], 1);
  }
  // x -> bf16 self-slice of A1 (exact path through Wr) AND dense fp8 X8 (gather source)
  const size_t nq = (size_t)n_nodes * IN_DIM / 4;
  for (size_t q = tid; q < nq; q += nt) {
    const int row = (int)(q >> 5), j = (int)(q & 31) * 4;
    __hip_bfloat16* dstp = A1 + (size_t)row * 384 + 256 + j;
    float f0, f1, f2, f3;
    if (bf) {
      uint2 v = ((const uint2*)x)[q];
      *(uint2*)dstp = v;
      f0 = blo(v.x); f1 = bhi(v.x); f2 = blo(v.y); f3 = bhi(v.y);
    } else {
      float4 v = ((const float4*)x)[q];
      unsigned short o[4] = {f2bf(v.x), f2bf(v.y), f2bf(v.z), f2bf(v.w)};
      *(uint2*)dstp = *(uint2*)o;
      f0 = v.x; f1 = v.y; f2 = v.z; f3 = v.w;
    }
    int p8 = __builtin_amdgcn_cvt_pk_fp8_f32(f0, f1, 0, false);
    p8 = __builtin_amdgcn_cvt_pk_fp8_f32(f2, f3, p8, true);
    *(int*)(X8 + (size_t)row * 128 + j) = p8;
  }
  for (int idx = tid; idx < 768 * 256; idx += nt) {
    {
      int j = idx & 7, l = (idx >> 3) & 63, rest = idx >> 9;
      int s = rest % 48, t = rest / 48;
      int k = s * 16 + (l >> 5) * 8 + j, col = t * 32 + (l & 31);
      float v;
      if (k < 256)      v = ld_f(Wl_f2, (size_t)k * 256 + col, bf);
      else if (k < 512) v = ld_f(Wl_b2, (size_t)(k - 256) * 256 + col, bf);
      else              v = ld_f(Wr_f2, (size_t)(k - 512) * 256 + col, bf) +
                            ld_f(Wr_b2, (size_t)(k - 512) * 256 + col, bf);
      Wpk2[idx] = __float2bfloat16(v);
    }
    if (idx < 384 * 256) {
      int j = idx & 7, l = (idx >> 3) & 63, rest = idx >> 9;
      int s = rest % 24, t = rest / 24;
      int k = s * 16 + (l >> 5) * 8 + j, col = t * 32 + (l & 31);
      float v;
      if (k < 128)      v = ld_f(Wl_f1, (size_t)k * 256 + col, bf);
      else if (k < 256) v = ld_f(Wl_b1, (size_t)(k - 128) * 256 + col, bf);
      else              v = ld_f(Wr_f1, (size_t)(k - 256) * 256 + col, bf) +
                            ld_f(Wr_b1, (size_t)(k - 256) * 256 + col, bf);
      Wpk1[idx] = __float2bfloat16(v);
    }
    if (idx < 256) {
      b1[idx] = ld_f(bl_f1, idx, bf) + ld_f(bl_b1, idx, bf);
      b2[idx] = ld_f(bl_f2, idx, bf) + ld_f(bl_b2, idx, bf);
      gamma1[idx] = ld_f(g1, idx, bf);
      beta1[idx]  = ld_f(be1, idx, bf);
      gamma2[idx] = ld_f(g2, idx, bf);
      beta2[idx]  = ld_f(be2, idx, bf);
    }
  }
}

// ---------- CSR build ----------
__global__ void scan_part_kernel(const int* __restrict__ degf, const int* __restrict__ degb,
                                 int* __restrict__ offf, int* __restrict__ offb,
                                 int* __restrict__ partials, int n, int nb) {
  __shared__ int buf[256];
  const int b = blockIdx.x;
  const int* deg = (b < nb) ? degf : degb;
  int* off = (b < nb) ? offf : offb;
  const int chunk = (b < nb) ? b : (b - nb);
  const int i = chunk * 256 + threadIdx.x;
  int v = (i < n) ? deg[i] : 0;
  buf[threadIdx.x] = v;
  __syncthreads();
  for (int s = 1; s < 256; s <<= 1) {
    int t = (threadIdx.x >= s) ? buf[threadIdx.x - s] : 0;
    __syncthreads();
    buf[threadIdx.x] += t;
    __syncthreads();
  }
  if (i < n) off[i] = buf[threadIdx.x] - v;
  if (threadIdx.x == 255) partials[b] = buf[255];
}

__global__ void scan_add_kernel(int* __restrict__ offf, int* __restrict__ offb,
                                const int* __restrict__ partials, int n, int nb, int n_edges) {
  __shared__ int red[256];
  const int b = blockIdx.x;
  int* off = (b < nb) ? offf : offb;
  const int chunk = (b < nb) ? b : (b - nb);
  const int abase = (b < nb) ? 0 : nb;
  int v = (threadIdx.x < chunk) ? partials[abase + threadIdx.x] : 0;
  red[threadIdx.x] = v;
  __syncthreads();
  for (int s = 128; s > 0; s >>= 1) {
    if (threadIdx.x < s) red[threadIdx.x] += red[threadIdx.x + s];
    __syncthreads();
  }
  const int prefix = red[0];
  const int i = chunk * 256 + threadIdx.x;
  if (i < n) off[i] += prefix;
  if (b == 0 && threadIdx.x == 0) { offf[n] = n_edges; offb[n] = n_edges; }
}

// ---------- atomic-free edge placement ----------
__global__ void fill_adj_kernel(const void* __restrict__ ei,
                                const int* __restrict__ rankf, const int* __restrict__ rankb,
                                const int* __restrict__ offf, const int* __restrict__ offb,
                                int* __restrict__ adjf, int* __restrict__ adjb, int n_edges) {
  __shared__ int nz;
  if (threadIdx.x == 0) nz = 0;
  __syncthreads();
  if (((const unsigned*)ei)[2 * threadIdx.x + 1] != 0u) atomicAdd(&nz, 1);
  __syncthreads();
  const int i32 = nz > 0;
  int i = blockIdx.x * 256 + threadIdx.x;
  if (i >= n_edges) return;
  int s, d;
  if (i32) { s = ((const int*)ei)[i]; d = ((const int*)ei)[n_edges + i]; }
  else     { s = (int)((const long long*)ei)[i]; d = (int)((const long long*)ei)[n_edges + i]; }
  adjf[offf[d] + rankf[i]] = s;
  adjb[offb[s] + rankb[i]] = d;
}

// ---------- gather-mean fp8, layer 1: X8[n][128] -> bf16 mean slices of A1 ----------
__global__ __launch_bounds__(256) void gather_mean_x8_kernel(
    const unsigned char* __restrict__ Q,  // [n_nodes][128] fp8 e4m3
    __hip_bfloat16* __restrict__ A1,      // row stride 384
    const int* __restrict__ adjf, const int* __restrict__ offf,
    const int* __restrict__ adjb, const int* __restrict__ offb, int n_nodes) {
  const int gw = (int)(((size_t)blockIdx.x * 256 + threadIdx.x) >> 6);
  const int lane = threadIdx.x & 63;
  if (gw >= 2 * n_nodes) return;
  int node, dir;
  const int *adj, *off;
  if (gw < n_nodes) { node = gw;           adj = adjf; off = offf; dir = 0; }
  else              { node = gw - n_nodes; adj = adjb; off = offb; dir = 1; }
  const int s = off[node], e = off[node + 1];
  const int sub = lane >> 4, cl = lane & 15;  // 4 subs x 16 col-lanes (8 cols each)
  auto clampi = [&](int i) { return max(min(i, e - 1), 0); };
  auto ROW = [&](int a) { return *(const uint2*)(Q + (size_t)a * 128 + cl * 8); };
  float acc[8] = {0.f, 0.f, 0.f, 0.f, 0.f, 0.f, 0.f, 0.f};
  int i = s + sub;
  int a0 = adj[clampi(i)];
  int a1 = adj[clampi(i + 4)];
  int a2 = adj[clampi(i + 8)];
  int a3 = adj[clampi(i + 12)];
  uint2 r0 = ROW(a0);
  uint2 r1 = ROW(a1);
  for (; i < e; i += 8) {
    const uint2 r2 = ROW(a2), r3 = ROW(a3);  // next pair in flight
    const int a4 = adj[clampi(i + 16)];
    const int a5 = adj[clampi(i + 20)];
    {
      f32x2 p;
      p = __builtin_amdgcn_cvt_pk_f32_fp8((int)r0.x, false); acc[0] += p.x; acc[1] += p.y;
      p = __builtin_amdgcn_cvt_pk_f32_fp8((int)r0.x, true);  acc[2] += p.x; acc[3] += p.y;
      p = __builtin_amdgcn_cvt_pk_f32_fp8((int)r0.y, false); acc[4] += p.x; acc[5] += p.y;
      p = __builtin_amdgcn_cvt_pk_f32_fp8((int)r0.y, true);  acc[6] += p.x; acc[7] += p.y;
    }
    if (i + 4 < e) {
      f32x2 p;
      p = __builtin_amdgcn_cvt_pk_f32_fp8((int)r1.x, false); acc[0] += p.x; acc[1] += p.y;
      p = __builtin_amdgcn_cvt_pk_f32_fp8((int)r1.x, true);  acc[2] += p.x; acc[3] += p.y;
      p = __builtin_amdgcn_cvt_pk_f32_fp8((int)r1.y, false); acc[4] += p.x; acc[5] += p.y;
      p = __builtin_amdgcn_cvt_pk_f32_fp8((int)r1.y, true);  acc[6] += p.x; acc[7] += p.y;
    }
    r0 = r2; r1 = r3; a2 = a4; a3 = a5;
  }
#pragma unroll
  for (int o = 32; o >= 16; o >>= 1) {
#pragma unroll
    for (int k = 0; k < 8; ++k) acc[k] += __shfl_xor(acc[k], o, 64);
  }
  if (sub == 0) {
    const float inv = 1.0f / (float)max(e - s, 1);
    union { unsigned short us[8]; uint4 v; } o;
#pragma unroll
    for (int k = 0; k < 8; ++k) o.us[k] = f2bf(acc[k] * inv);
    *(uint4*)(A1 + (size_t)node * 384 + dir * 128 + cl * 8) = o.v;
  }
}

// ---------- gather-mean fp8, layer 2 (r5-measured; unchanged) ----------
__global__ __launch_bounds__(256) void gather_mean_q8_kernel(
    const unsigned char* __restrict__ Q,  // [n_nodes][256] fp8 e4m3
    __hip_bfloat16* __restrict__ A,       // A2, row stride 768
    const int* __restrict__ adjf, const int* __restrict__ offf,
    const int* __restrict__ adjb, const int* __restrict__ offb, int n_nodes) {
  const int gw = (int)(((size_t)blockIdx.x * 256 + threadIdx.x) >> 6);
  const int lane = threadIdx.x & 63;
  if (gw >= 2 * n_nodes) return;
  int node, dir;
  const int *adj, *off;
  if (gw < n_nodes) { node = gw;           adj = adjf; off = offf; dir = 0; }
  else              { node = gw - n_nodes; adj = adjb; off = offb; dir = 1; }
  const int s = off[node], e = off[node + 1];
  const int sub = lane >> 5, cl = lane & 31;
  auto clampi = [&](int i) { return max(min(i, e - 1), 0); };
  auto ROW = [&](int a) { return *(const uint2*)(Q + (size_t)a * 256 + cl * 8); };
  float acc[8] = {0.f, 0.f, 0.f, 0.f, 0.f, 0.f, 0.f, 0.f};
  int i = s + sub;
  int a0 = adj[clampi(i)];
  int a1 = adj[clampi(i + 2)];
  int a2 = adj[clampi(i + 4)];
  int a3 = adj[clampi(i + 6)];
  uint2 r0 = ROW(a0);
  uint2 r1 = ROW(a1);
  for (; i < e; i += 4) {
    const uint2 r2 = ROW(a2), r3 = ROW(a3);
    const int a4 = adj[clampi(i + 8)];
    const int a5 = adj[clampi(i + 10)];
    {
      f32x2 p;
      p = __builtin_amdgcn_cvt_pk_f32_fp8((int)r0.x, false); acc[0] += p.x; acc[1] += p.y;
      p = __builtin_amdgcn_cvt_pk_f32_fp8((int)r0.x, true);  acc[2] += p.x; acc[3] += p.y;
      p = __builtin_amdgcn_cvt_pk_f32_fp8((int)r0.y, false); acc[4] += p.x; acc[5] += p.y;
      p = __builtin_amdgcn_cvt_pk_f32_fp8((int)r0.y, true);  acc[6] += p.x; acc[7] += p.y;
    }
    if (i + 2 < e) {
      f32x2 p;
      p = __builtin_amdgcn_cvt_pk_f32_fp8((int)r1.x, false); acc[0] += p.x; acc[1] += p.y;
      p = __builtin_amdgcn_cvt_pk_f32_fp8((int)r1.x, true);  acc[2] += p.x; acc[3] += p.y;
      p = __builtin_amdgcn_cvt_pk_f32_fp8((int)r1.y, false); acc[4] += p.x; acc[5] += p.y;
      p = __builtin_amdgcn_cvt_pk_f32_fp8((int)r1.y, true);  acc[6] += p.x; acc[7] += p.y;
    }
    r0 = r2; r1 = r3; a2 = a4; a3 = a5;
  }
#pragma unroll
  for (int k = 0; k < 8; ++k) acc[k] += __shfl_xor(acc[k], 32, 64);
  if (sub == 0) {
    const float inv = 1.0f / (float)max(e - s, 1);
    union { unsigned short us[8]; uint4 v; } o;
#pragma unroll
    for (int k = 0; k < 8; ++k) o.us[k] = f2bf(acc[k] * inv);
    *(uint4*)(A + (size_t)node * 768 + dir * 256 + cl * 8) = o.v;
  }
}

// ---------- MFMA GEMM, M128 tile (r5 measured-best for layer 1; unchanged) ----------
template <int K, bool STORE>
__global__ __launch_bounds__(256, 2) void gemm_mfma128_kernel(
    const __hip_bfloat16* __restrict__ A, const __hip_bfloat16* __restrict__ Wpk,
    const float* __restrict__ bias, __hip_bfloat16* __restrict__ Cb,
    float* __restrict__ bnsum, float* __restrict__ bnsum2,
    unsigned* __restrict__ gmax, unsigned* __restrict__ gmin, int M) {
  constexpr int S = K / 16;
  constexpr int NIT = K / 128;
  __shared__ __align__(16) union SMem {
    char at[2][32768];
    struct { float colsum[256], colsum2[256]; unsigned cmax[256], cmin[256]; } st;
  } sm;
  const int wave = threadIdx.x >> 6, lane = threadIdx.x & 63;
  const int rw = wave >> 1, cw = wave & 1;
  const int rbase = blockIdx.x * 128;
  const char* gsrc = (const char*)(A + (size_t)(rbase + wave * 32 + (lane & 31)) * K)
                   + (lane >> 5) * 16;
  char* lb[2] = { &sm.at[0][wave * 1024], &sm.at[1][wave * 1024] };

  {
#pragma unroll
    for (int d = 0; d < 8; ++d) load_lds16(gsrc + d * 32, lb[0] + d * 4096);
  }

  const __hip_bfloat16* wbase = Wpk + ((size_t)(cw * 4) * S * 64 + lane) * 8;
  f32x16 acc[2][4] = {};

  for (int kb = 0; kb < NIT; ++kb) {
    __syncthreads();
    if (kb + 1 < NIT) {
      const char* g = gsrc + (size_t)(kb + 1) * 256;
      char* l = lb[(kb + 1) & 1];
#pragma unroll
      for (int d = 0; d < 8; ++d) load_lds16(g + d * 32, l + d * 4096);
    }
    const char* ab = sm.at[kb & 1];
#pragma unroll
    for (int s = 0; s < 8; ++s) {
      const int ks = kb * 8 + s;
      const bf16x8 a0 = *(const bf16x8*)(ab + (s * 4 + rw * 2 + 0) * 1024 + lane * 16);
      const bf16x8 a1 = *(const bf16x8*)(ab + (s * 4 + rw * 2 + 1) * 1024 + lane * 16);
      const bf16x8 w0 = *(const bf16x8*)(wbase + ((size_t)0 * S + ks) * 512);
      const bf16x8 w1 = *(const bf16x8*)(wbase + ((size_t)1 * S + ks) * 512);
      const bf16x8 w2 = *(const bf16x8*)(wbase + ((size_t)2 * S + ks) * 512);
      const bf16x8 w3 = *(const bf16x8*)(wbase + ((size_t)3 * S + ks) * 512);
      acc[0][0] = __builtin_amdgcn_mfma_f32_32x32x16_bf16(a0, w0, acc[0][0], 0, 0, 0);
      acc[0][1] = __builtin_amdgcn_mfma_f32_32x32x16_bf16(a0, w1, acc[0][1], 0, 0, 0);
      acc[0][2] = __builtin_amdgcn_mfma_f32_32x32x16_bf16(a0, w2, acc[0][2], 0, 0, 0);
      acc[0][3] = __builtin_amdgcn_mfma_f32_32x32x16_bf16(a0, w3, acc[0][3], 0, 0, 0);
      acc[1][0] = __builtin_amdgcn_mfma_f32_32x32x16_bf16(a1, w0, acc[1][0], 0, 0, 0);
      acc[1][1] = __builtin_amdgcn_mfma_f32_32x32x16_bf16(a1, w1, acc[1][1], 0, 0, 0);
      acc[1][2] = __builtin_amdgcn_mfma_f32_32x32x16_bf16(a1, w2, acc[1][2], 0, 0, 0);
      acc[1][3] = __builtin_amdgcn_mfma_f32_32x32x16_bf16(a1, w3, acc[1][3], 0, 0, 0);
    }
  }

  __syncthreads();
  sm.st.colsum[threadIdx.x] = 0.f;
  sm.st.colsum2[threadIdx.x] = 0.f;
  if (!STORE) { sm.st.cmax[threadIdx.x] = 0u; sm.st.cmin[threadIdx.x] = 0u; }
  __syncthreads();

#pragma unroll
  for (int rh = 0; rh < 2; ++rh) {
#pragma unroll
    for (int t = 0; t < 4; ++t) {
      const int col = cw * 128 + t * 32 + (lane & 31);
      const float bj = bias[col];
      float ls = 0.f, ls2 = 0.f, lmax = -INFINITY, lmin = INFINITY;
#pragma unroll
      for (int r = 0; r < 16; ++r) {
        const int row = rbase + rw * 64 + rh * 32 + (r & 3) + 8 * (r >> 2) + 4 * (lane >> 5);
        if (row < M) {
          float v = acc[rh][t][r] + bj;
          if (STORE) Cb[(size_t)row * 768 + 512 + col] = __float2bfloat16(v);
          ls += v;
          ls2 = fmaf(v, v, ls2);
          if (!STORE) { lmax = fmaxf(lmax, v); lmin = fminf(lmin, v); }
        }
      }
      atomicAdd(&sm.st.colsum[col], ls);
      atomicAdd(&sm.st.colsum2[col], ls2);
      if (!STORE) {
        atomicMax(&sm.st.cmax[col], fkey(lmax));
        atomicMax(&sm.st.cmin[col], ~fkey(lmin));
      }
    }
  }
  __syncthreads();
  atomicAdd(&bnsum[threadIdx.x], sm.st.colsum[threadIdx.x]);
  atomicAdd(&bnsum2[threadIdx.x], sm.st.colsum2[threadIdx.x]);
  if (!STORE) {
    atomicMax(&gmax[threadIdx.x], sm.st.cmax[threadIdx.x]);
    atomicMax(&gmin[threadIdx.x], sm.st.cmin[threadIdx.x]);
  }
}

// ---------- MFMA GEMM, persistent W-in-registers + counted-vmcnt ring pipeline ----------
// r10: W-in-reg (AGPR) worked (47.9us best) but A-staging is HBM-latency-bound: each
// __syncthreads drains vmcnt(0), serializing 6 stage->wait cycles per tile at ~900cyc.
// Fix (T3/T4): 3-slot LDS ring, stage step t+2 while computing t, wait vmcnt(8) (NOT 0)
// so 2 k-blocks of DMAs stay in flight across raw s_barriers. NIT=6 = 0 mod 3 -> ring
// slot = kb%3 and stage slot = (kb+2)%3 are COMPILE-TIME (rule #20 safe); wr[] indices
// compile-time via unrolled kb. Prologue drains vmcnt(0) once so the W-hoist loads
// don't pollute the in-loop count. sched_barrier(0) after waitcnt per rule #18.
template <int K, int NBS>
__global__ __launch_bounds__(256, 2) void gemm_persist_kernel(
    const __hip_bfloat16* __restrict__ A, const __hip_bfloat16* __restrict__ Wpk,
    const float* __restrict__ bias,
    float* __restrict__ bnsum, float* __restrict__ bnsum2,
    unsigned* __restrict__ gmax, unsigned* __restrict__ gmin, int M, int ntiles) {
  constexpr int S = K / 16;    // 48 k-steps
  constexpr int NIT = K / 128; // 6 BK iterations (== 0 mod 3)
  static_assert(NIT % 3 == 0, "ring indexing requires NIT % 3 == 0");
  __shared__ __align__(16) union SMem {
    char at[3][16384];  // 3-slot ring: 64 rows x BK=128 x 2B each
    struct { float colsum[256], colsum2[256]; unsigned cmax[256], cmin[256]; } st;
  } sm;
  const int wave = threadIdx.x >> 6, lane = threadIdx.x & 63;
  const int cg = (int)(blockIdx.x & 1);       // col-group: cols [cg*128, cg*128+128)
  const int bstart = (int)(blockIdx.x >> 1);  // first m-tile
  const int ct = cg * 4 + wave;               // this wave's 32-col tile

  // hoist this wave's full-K W into registers (lands in AGPRs), once per block
  bf16x8 wr[S];
#pragma unroll
  for (int d = 0; d < S; ++d)
    wr[d] = *(const bf16x8*)(Wpk + ((size_t)ct * S + d) * 512 + lane * 8);

  const int col = ct * 32 + (lane & 31);
  const float bj = bias[col];
  float ls = 0.f, ls2 = 0.f, lmax = -INFINITY, lmin = INFINITY;
  const size_t rh_off = (size_t)64 * K;  // 32 rows * K * 2B (byte offset)

  int ntb = 0;
  for (int m = bstart; m < ntiles; m += NBS) ++ntb;

  // stage (mi, kb) into ring slot; slot passed as compile-time constant by callers
  auto STAGE = [&](int mi, int kb, int slot) {
    const int rbase = (bstart + mi * NBS) * 64;
    const char* gs = (const char*)(A + (size_t)(rbase + (lane & 31)) * K) + (lane >> 5) * 16;
    char* buf = sm.at[slot];
#pragma unroll
    for (int ss = 0; ss < 2; ++ss) {
      const int s = wave * 2 + ss;
      const char* g = gs + (size_t)kb * 256 + s * 32;
      load_lds16(g,          buf + (s * 2 + 0) * 1024);
      load_lds16(g + rh_off, buf + (s * 2 + 1) * 1024);
    }
  };

  if (ntb > 0) {
    STAGE(0, 0, 0);
    STAGE(0, 1, 1);
    asm volatile("s_waitcnt vmcnt(0)" ::: "memory");  // drain W-hoist + prologue stages
    __builtin_amdgcn_s_barrier();
  }

  for (int mi = 0; mi < ntb; ++mi) {
    f32x16 acc[2] = {};
#pragma unroll
    for (int kb = 0; kb < NIT; ++kb) {
      // stage step t+2 (tile/kb arithmetic compile-time in kb)
      constexpr int dmi_tab = 0;  // (kb+2)/NIT handled below
      const int s_kb = (kb + 2 < NIT) ? (kb + 2) : (kb + 2 - NIT);
      const int s_mi = mi + ((kb + 2) >= NIT ? 1 : 0);
      const bool have2 = (s_mi < ntb);
      const bool have1 = !(mi == ntb - 1 && kb == NIT - 1);
      if (have2) STAGE(s_mi, s_kb, (kb + 2) % 3);
      if (have2)      asm volatile("s_waitcnt vmcnt(8)" ::: "memory");
      else if (have1) asm volatile("s_waitcnt vmcnt(4)" ::: "memory");
      else            asm volatile("s_waitcnt vmcnt(0)" ::: "memory");
      __builtin_amdgcn_sched_barrier(0);
      __builtin_amdgcn_s_barrier();  // all waves' step-t DMAs landed
      const char* ab = sm.at[kb % 3];
#pragma unroll
      for (int s = 0; s < 8; ++s) {
        const bf16x8 a0 = *(const bf16x8*)(ab + (s * 2 + 0) * 1024 + lane * 16);
        const bf16x8 a1 = *(const bf16x8*)(ab + (s * 2 + 1) * 1024 + lane * 16);
        const bf16x8 w = wr[kb * 8 + s];  // compile-time index
        acc[0] = __builtin_amdgcn_mfma_f32_32x32x16_bf16(a0, w, acc[0], 0, 0, 0);
        acc[1] = __builtin_amdgcn_mfma_f32_32x32x16_bf16(a1, w, acc[1], 0, 0, 0);
      }
      asm volatile("s_waitcnt lgkmcnt(0)" ::: "memory");  // reads of slot kb%3 complete
      __builtin_amdgcn_sched_barrier(0);
      __builtin_amdgcn_s_barrier();  // safe for step t+3 to overwrite slot kb%3
      (void)dmi_tab;
    }
    const int rbase = (bstart + mi * NBS) * 64;
#pragma unroll
    for (int rh = 0; rh < 2; ++rh) {
#pragma unroll
      for (int r = 0; r < 16; ++r) {
        const int row = rbase + rh * 32 + (r & 3) + 8 * (r >> 2) + 4 * (lane >> 5);
        if (row < M) {
          float v = acc[rh][r] + bj;
          ls += v;
          ls2 = fmaf(v, v, ls2);
          lmax = fmaxf(lmax, v);
          lmin = fminf(lmin, v);
        }
      }
    }
  }

  // single stats epilogue (LDS aliased after the loop's final barrier)
  __syncthreads();
  sm.st.colsum[threadIdx.x] = 0.f;
  sm.st.colsum2[threadIdx.x] = 0.f;
  sm.st.cmax[threadIdx.x] = 0u;
  sm.st.cmin[threadIdx.x] = 0u;
  __syncthreads();
  atomicAdd(&sm.st.colsum[col], ls);
  atomicAdd(&sm.st.colsum2[col], ls2);
  atomicMax(&sm.st.cmax[col], fkey(lmax));
  atomicMax(&sm.st.cmin[col], ~fkey(lmin));
  __syncthreads();
  atomicAdd(&bnsum[threadIdx.x], sm.st.colsum[threadIdx.x]);
  atomicAdd(&bnsum2[threadIdx.x], sm.st.colsum2[threadIdx.x]);
  atomicMax(&gmax[threadIdx.x], sm.st.cmax[threadIdx.x]);
  atomicMax(&gmin[threadIdx.x], sm.st.cmin[threadIdx.x]);
}

// ---------- BN+ReLU in place on A2 self-slice + fp8 shadow for the layer-2 gather ----------
__global__ void bn_apply_kernel(__hip_bfloat16* __restrict__ A2,
                                unsigned char* __restrict__ A2q,
                                const float* __restrict__ sum, const float* __restrict__ sumsq,
                                const float* __restrict__ gamma, const float* __restrict__ beta,
                                int n_nodes, float inv_n) {
  const int j0 = (threadIdx.x & 63) * 4;
  const int row = blockIdx.x * 4 + (threadIdx.x >> 6);
  if (row >= n_nodes) return;
  float g[4], b[4];
#pragma unroll
  for (int k = 0; k < 4; ++k) {
    const int j = j0 + k;
    float mu = sum[j] * inv_n;
    float rs = rsqrtf(fmaxf(sumsq[j] * inv_n - mu * mu, 0.f) + BN_EPS);
    g[k] = gamma[j] * rs;
    b[k] = fmaf(-mu, g[k], beta[j]);
  }
  uint2* p = (uint2*)(A2 + (size_t)row * 768 + 512 + j0);
  uint2 w = *p;
  float h[4];
  h[0] = fmaxf(fmaf(blo(w.x), g[0], b[0]), 0.f);
  h[1] = fmaxf(fmaf(bhi(w.x), g[1], b[1]), 0.f);
  h[2] = fmaxf(fmaf(blo(w.y), g[2], b[2]), 0.f);
  h[3] = fmaxf(fmaf(bhi(w.y), g[3], b[3]), 0.f);
  unsigned short us[4] = {f2bf(h[0]), f2bf(h[1]), f2bf(h[2]), f2bf(h[3])};
  *p = *(uint2*)us;
  int q8 = __builtin_amdgcn_cvt_pk_fp8_f32(h[0], h[1], 0, false);
  q8 = __builtin_amdgcn_cvt_pk_fp8_f32(h[2], h[3], q8, true);
  *(int*)(A2q + (size_t)row * 256 + j0) = q8;
}

// ---------- finalize ----------
__global__ void finalize_kernel(const unsigned* __restrict__ xw,
                                const float* __restrict__ sum, const float* __restrict__ sumsq,
                                const unsigned* __restrict__ gmax, const unsigned* __restrict__ gmin,
                                const float* __restrict__ gamma, const float* __restrict__ beta,
                                float inv_n, void* __restrict__ out, int out_size) {
  __shared__ int votes;
  if (threadIdx.x == 0) votes = 0;
  __syncthreads();
  unsigned e = (xw[threadIdx.x] >> 7) & 0xFFu;
  if (e >= 100u && e <= 140u) atomicAdd(&votes, 1);
  __syncthreads();
  int bf = votes > 128;
  int j = threadIdx.x;
  if (j >= out_size) return;
  float mu = sum[j] * inv_n;
  float rs = rsqrtf(fmaxf(sumsq[j] * inv_n - mu * mu, 0.f) + BN_EPS);
  float g = gamma[j] * rs, b = fmaf(-mu, g, beta[j]);
  float vmax = finv(gmax[j]);
  float vmin = finv(~gmin[j]);
  float v = fmaxf(fmaf(g, (g >= 0.f) ? vmax : vmin, b), 0.f);
  if (bf) ((__hip_bfloat16*)out)[j] = __float2bfloat16(v);
  else    ((float*)out)[j] = v;
}

extern "C" void kernel_launch(void* const* d_in, const int* in_sizes, int n_in,
                              void* d_out, int out_size, void* d_ws, size_t ws_size,
                              hipStream_t stream) {
  const void* x  = d_in[0];
  const void* ei = d_in[1];
  const int n_nodes = in_sizes[0] / IN_DIM;
  const int n_edges = in_sizes[1] / 2;
  const int nb = (n_nodes + 255) / 256;
  const int Mpad = (n_nodes + 127) & ~127;

  float* ws = (float*)d_ws;
  size_t off = 0;
  auto alloc = [&](size_t n) {
    float* p = ws + off;
    off += (n + 1023) & ~(size_t)1023;
    return p;
  };
  __hip_bfloat16* Wpk1 = (__hip_bfloat16*)alloc(384 * 256 / 2);
  __hip_bfloat16* Wpk2 = (__hip_bfloat16*)alloc(768 * 256 / 2);
  float* b1      = alloc(256);
  float* b2      = alloc(256);
  float* gamma1  = alloc(256);
  float* beta1   = alloc(256);
  float* gamma2  = alloc(256);
  float* beta2   = alloc(256);
  float* zeros   = alloc(2 * (size_t)n_nodes + 2048);
  int*   degf    = (int*)zeros;
  int*   degb    = degf + n_nodes;
  float* sum1    = zeros + 2 * (size_t)n_nodes;
  float* sumsq1  = sum1 + 256;
  float* sum2    = sum1 + 512;
  float* sumsq2  = sum1 + 768;
  unsigned* max2 = (unsigned*)(sum1 + 1024);
  unsigned* min2 = (unsigned*)(sum1 + 1280);
  int*   offf    = (int*)alloc(n_nodes + 1);
  int*   offb    = (int*)alloc(n_nodes + 1);
  int*   rankf   = (int*)alloc(n_edges);
  int*   rankb   = (int*)alloc(n_edges);
  int*   adjf    = (int*)alloc(n_edges);
  int*   adjb    = (int*)alloc(n_edges);
  int*   partials = (int*)alloc(2 * nb);
  unsigned char* X8 = (unsigned char*)alloc((size_t)n_nodes * 32);  // [n][128] fp8 of x
  __hip_bfloat16* A1 = (__hip_bfloat16*)alloc((size_t)Mpad * 384 / 2);
  __hip_bfloat16* A2 = (__hip_bfloat16*)alloc((size_t)Mpad * 768 / 2);
  // fp8 shadow of h for the layer-2 gather. Aliases A1 (dead after gemm1).
  unsigned char* A2q = (unsigned char*)A1;
  (void)ws_size; (void)n_in;

  hipMemsetAsync(zeros, 0, (2 * (size_t)n_nodes + 2048) * 4, stream);

  const int pgrid = (n_edges + 255) / 256;
  prep_kernel<<<pgrid, 256, 0, stream>>>(
      x, ei,
      d_in[2], d_in[3], d_in[4], d_in[5], d_in[6], d_in[7],
      d_in[8], d_in[9], d_in[10], d_in[11], d_in[12], d_in[13],
      d_in[14], d_in[15], d_in[16], d_in[17],
      degf, degb, rankf, rankb, A1, X8,
      Wpk1, b1, Wpk2, b2, gamma1, beta1, gamma2, beta2, n_nodes, n_edges);

  scan_part_kernel<<<2 * nb, 256, 0, stream>>>(degf, degb, offf, offb, partials, n_nodes, nb);
  scan_add_kernel<<<2 * nb, 256, 0, stream>>>(offf, offb, partials, n_nodes, nb, n_edges);
  fill_adj_kernel<<<(n_edges + 255) / 256, 256, 0, stream>>>(
      ei, rankf, rankb, offf, offb, adjf, adjb, n_edges);

  const float inv_n = 1.0f / (float)n_nodes;
  const int ggrid = (2 * n_nodes + 3) / 4;

  // ---- layer 1 (fp8-source gather, M128 GEMM) ----
  gather_mean_x8_kernel<<<ggrid, 256, 0, stream>>>(
      X8, A1, adjf, offf, adjb, offb, n_nodes);
  gemm_mfma128_kernel<384, true><<<Mpad / 128, 256, 0, stream>>>(
      A1, Wpk1, b1, A2, sum1, sumsq1, max2, min2, n_nodes);
  bn_apply_kernel<<<(n_nodes + 3) / 4, 256, 0, stream>>>(
      A2, A2q, sum1, sumsq1, gamma1, beta1, n_nodes, inv_n);

  // ---- layer 2 (fp8-source gather, persistent counted-vmcnt GEMM) ----
  gather_mean_q8_kernel<<<ggrid, 256, 0, stream>>>(
      A2q, A2, adjf, offf, adjb, offb, n_nodes);
  gemm_persist_kernel<768, 256><<<2 * 256, 256, 0, stream>>>(
      A2, Wpk2, b2, sum2, sumsq2, max2, min2, n_nodes, Mpad / 64);
  finalize_kernel<<<1, 256, 0, stream>>>(
      (const unsigned*)x, sum2, sumsq2, max2, min2, gamma2, beta2, inv_n, d_out, out_size);
}

// Round 12
// 321.239 us; speedup vs baseline: 1.1322x; 1.0083x over previous
//
#include <hip/hip_runtime.h>
#include <hip/hip_bf16.h>

#define IN_DIM 128
#define HID 256
#define BN_EPS 1e-5f

typedef __attribute__((ext_vector_type(8))) short bf16x8;
typedef __attribute__((ext_vector_type(16))) float f32x16;
typedef __attribute__((ext_vector_type(2))) float f32x2;

// ---------- helpers ----------
__device__ __forceinline__ float ld_f(const void* p, size_t i, int bf16) {
  if (bf16) return __bfloat162float(((const __hip_bfloat16*)p)[i]);
  return ((const float*)p)[i];
}
__device__ __forceinline__ float blo(unsigned u) { return __uint_as_float(u << 16); }
__device__ __forceinline__ float bhi(unsigned u) { return __uint_as_float(u & 0xffff0000u); }
__device__ __forceinline__ unsigned short f2bf(float f) {
  __hip_bfloat16 b = __float2bfloat16(f);
  return __builtin_bit_cast(unsigned short, b);
}
__device__ __forceinline__ void load_lds16(const void* g, void* l) {
  __builtin_amdgcn_global_load_lds((const __attribute__((address_space(1))) void*)g,
                                   (__attribute__((address_space(3))) void*)l, 16, 0, 0);
}
// order-preserving float->uint key (monotone increasing); init 0 is neutral for max
__device__ __forceinline__ unsigned fkey(float v) {
  unsigned s = __float_as_uint(v);
  return (s & 0x80000000u) ? ~s : (s | 0x80000000u);
}
__device__ __forceinline__ float finv(unsigned k) {
  unsigned s = (k & 0x80000000u) ? (k ^ 0x80000000u) : ~k;
  return __uint_as_float(s);
}

// ---------- prep A: edge histogram + per-edge rank (atomic return value) ----------
// Split from the old mega-prep so rocprof attributes its cost separately from the
// conversion/W-pack work (r11: fused prep = 46us, VALU 3%, unattributable).
__global__ void prep_edges_kernel(
    const void* __restrict__ ei,
    int* __restrict__ degf, int* __restrict__ degb,
    int* __restrict__ rankf, int* __restrict__ rankb, int n_edges) {
  __shared__ int nz;
  if (threadIdx.x == 0) nz = 0;
  __syncthreads();
  if (((const unsigned*)ei)[2 * threadIdx.x + 1] != 0u) atomicAdd(&nz, 1);
  __syncthreads();
  const int i32 = nz > 0;
  const int tid = blockIdx.x * 256 + threadIdx.x;
  const int nt = gridDim.x * 256;
  for (int i = tid; i < n_edges; i += nt) {
    int s, d;
    if (i32) { s = ((const int*)ei)[i]; d = ((const int*)ei)[n_edges + i]; }
    else     { s = (int)((const long long*)ei)[i]; d = (int)((const long long*)ei)[n_edges + i]; }
    rankf[i] = atomicAdd(&degf[d], 1);
    rankb[i] = atomicAdd(&degb[s], 1);
  }
}

// ---------- prep B: x -> A1 self-slice (bf16) + X8 (fp8) + W packs + biases ----------
__global__ void prep_x_kernel(
    const void* __restrict__ x,
    const void* Wl_f1, const void* bl_f1, const void* Wr_f1,
    const void* Wl_b1, const void* bl_b1, const void* Wr_b1,
    const void* Wl_f2, const void* bl_f2, const void* Wr_f2,
    const void* Wl_b2, const void* bl_b2, const void* Wr_b2,
    const void* g1, const void* be1, const void* g2, const void* be2,
    __hip_bfloat16* __restrict__ A1,
    unsigned char* __restrict__ X8,
    __hip_bfloat16* __restrict__ Wpk1, float* __restrict__ b1,
    __hip_bfloat16* __restrict__ Wpk2, float* __restrict__ b2,
    float* __restrict__ gamma1, float* __restrict__ beta1,
    float* __restrict__ gamma2, float* __restrict__ beta2,
    int n_nodes) {
  __shared__ int votes;
  if (threadIdx.x == 0) votes = 0;
  __syncthreads();
  {
    unsigned e = (((const unsigned*)x)[threadIdx.x] >> 7) & 0xFFu;
    if (e >= 100u && e <= 140u) atomicAdd(&votes, 1);
  }
  __syncthreads();
  const int bf = (votes > 128) ? 1 : 0;
  const int tid = blockIdx.x * 256 + threadIdx.x;
  const int nt = gridDim.x * 256;
  const size_t nq = (size_t)n_nodes * IN_DIM / 4;
  for (size_t q = tid; q < nq; q += nt) {
    const int row = (int)(q >> 5), j = (int)(q & 31) * 4;
    __hip_bfloat16* dstp = A1 + (size_t)row * 384 + 256 + j;
    float f0, f1, f2, f3;
    if (bf) {
      uint2 v = ((const uint2*)x)[q];
      *(uint2*)dstp = v;
      f0 = blo(v.x); f1 = bhi(v.x); f2 = blo(v.y); f3 = bhi(v.y);
    } else {
      float4 v = ((const float4*)x)[q];
      unsigned short o[4] = {f2bf(v.x), f2bf(v.y), f2bf(v.z), f2bf(v.w)};
      *(uint2*)dstp = *(uint2*)o;
      f0 = v.x; f1 = v.y; f2 = v.z; f3 = v.w;
    }
    int p8 = __builtin_amdgcn_cvt_pk_fp8_f32(f0, f1, 0, false);
    p8 = __builtin_amdgcn_cvt_pk_fp8_f32(f2, f3, p8, true);
    *(int*)(X8 + (size_t)row * 128 + j) = p8;
  }
  for (int idx = tid; idx < 768 * 256; idx += nt) {
    {
      int j = idx & 7, l = (idx >> 3) & 63, rest = idx >> 9;
      int s = rest % 48, t = rest / 48;
      int k = s * 16 + (l >> 5) * 8 + j, col = t * 32 + (l & 31);
      float v;
      if (k < 256)      v = ld_f(Wl_f2, (size_t)k * 256 + col, bf);
      else if (k < 512) v = ld_f(Wl_b2, (size_t)(k - 256) * 256 + col, bf);
      else              v = ld_f(Wr_f2, (size_t)(k - 512) * 256 + col, bf) +
                            ld_f(Wr_b2, (size_t)(k - 512) * 256 + col, bf);
      Wpk2[idx] = __float2bfloat16(v);
    }
    if (idx < 384 * 256) {
      int j = idx & 7, l = (idx >> 3) & 63, rest = idx >> 9;
      int s = rest % 24, t = rest / 24;
      int k = s * 16 + (l >> 5) * 8 + j, col = t * 32 + (l & 31);
      float v;
      if (k < 128)      v = ld_f(Wl_f1, (size_t)k * 256 + col, bf);
      else if (k < 256) v = ld_f(Wl_b1, (size_t)(k - 128) * 256 + col, bf);
      else              v = ld_f(Wr_f1, (size_t)(k - 256) * 256 + col, bf) +
                            ld_f(Wr_b1, (size_t)(k - 256) * 256 + col, bf);
      Wpk1[idx] = __float2bfloat16(v);
    }
    if (idx < 256) {
      b1[idx] = ld_f(bl_f1, idx, bf) + ld_f(bl_b1, idx, bf);
      b2[idx] = ld_f(bl_f2, idx, bf) + ld_f(bl_b2, idx, bf);
      gamma1[idx] = ld_f(g1, idx, bf);
      beta1[idx]  = ld_f(be1, idx, bf);
      gamma2[idx] = ld_f(g2, idx, bf);
      beta2[idx]  = ld_f(be2, idx, bf);
    }
  }
}

// ---------- CSR build ----------
__global__ void scan_part_kernel(const int* __restrict__ degf, const int* __restrict__ degb,
                                 int* __restrict__ offf, int* __restrict__ offb,
                                 int* __restrict__ partials, int n, int nb) {
  __shared__ int buf[256];
  const int b = blockIdx.x;
  const int* deg = (b < nb) ? degf : degb;
  int* off = (b < nb) ? offf : offb;
  const int chunk = (b < nb) ? b : (b - nb);
  const int i = chunk * 256 + threadIdx.x;
  int v = (i < n) ? deg[i] : 0;
  buf[threadIdx.x] = v;
  __syncthreads();
  for (int s = 1; s < 256; s <<= 1) {
    int t = (threadIdx.x >= s) ? buf[threadIdx.x - s] : 0;
    __syncthreads();
    buf[threadIdx.x] += t;
    __syncthreads();
  }
  if (i < n) off[i] = buf[threadIdx.x] - v;
  if (threadIdx.x == 255) partials[b] = buf[255];
}

__global__ void scan_add_kernel(int* __restrict__ offf, int* __restrict__ offb,
                                const int* __restrict__ partials, int n, int nb, int n_edges) {
  __shared__ int red[256];
  const int b = blockIdx.x;
  int* off = (b < nb) ? offf : offb;
  const int chunk = (b < nb) ? b : (b - nb);
  const int abase = (b < nb) ? 0 : nb;
  int v = (threadIdx.x < chunk) ? partials[abase + threadIdx.x] : 0;
  red[threadIdx.x] = v;
  __syncthreads();
  for (int s = 128; s > 0; s >>= 1) {
    if (threadIdx.x < s) red[threadIdx.x] += red[threadIdx.x + s];
    __syncthreads();
  }
  const int prefix = red[0];
  const int i = chunk * 256 + threadIdx.x;
  if (i < n) off[i] += prefix;
  if (b == 0 && threadIdx.x == 0) { offf[n] = n_edges; offb[n] = n_edges; }
}

// ---------- atomic-free edge placement ----------
__global__ void fill_adj_kernel(const void* __restrict__ ei,
                                const int* __restrict__ rankf, const int* __restrict__ rankb,
                                const int* __restrict__ offf, const int* __restrict__ offb,
                                int* __restrict__ adjf, int* __restrict__ adjb, int n_edges) {
  __shared__ int nz;
  if (threadIdx.x == 0) nz = 0;
  __syncthreads();
  if (((const unsigned*)ei)[2 * threadIdx.x + 1] != 0u) atomicAdd(&nz, 1);
  __syncthreads();
  const int i32 = nz > 0;
  int i = blockIdx.x * 256 + threadIdx.x;
  if (i >= n_edges) return;
  int s, d;
  if (i32) { s = ((const int*)ei)[i]; d = ((const int*)ei)[n_edges + i]; }
  else     { s = (int)((const long long*)ei)[i]; d = (int)((const long long*)ei)[n_edges + i]; }
  adjf[offf[d] + rankf[i]] = s;
  adjb[offb[s] + rankb[i]] = d;
}

// ---------- gather-mean fp8, layer 1: X8[n][128] -> bf16 mean slices of A1 ----------
__global__ __launch_bounds__(256) void gather_mean_x8_kernel(
    const unsigned char* __restrict__ Q,  // [n_nodes][128] fp8 e4m3
    __hip_bfloat16* __restrict__ A1,      // row stride 384
    const int* __restrict__ adjf, const int* __restrict__ offf,
    const int* __restrict__ adjb, const int* __restrict__ offb, int n_nodes) {
  const int gw = (int)(((size_t)blockIdx.x * 256 + threadIdx.x) >> 6);
  const int lane = threadIdx.x & 63;
  if (gw >= 2 * n_nodes) return;
  int node, dir;
  const int *adj, *off;
  if (gw < n_nodes) { node = gw;           adj = adjf; off = offf; dir = 0; }
  else              { node = gw - n_nodes; adj = adjb; off = offb; dir = 1; }
  const int s = off[node], e = off[node + 1];
  const int sub = lane >> 4, cl = lane & 15;  // 4 subs x 16 col-lanes (8 cols each)
  auto clampi = [&](int i) { return max(min(i, e - 1), 0); };
  auto ROW = [&](int a) { return *(const uint2*)(Q + (size_t)a * 128 + cl * 8); };
  float acc[8] = {0.f, 0.f, 0.f, 0.f, 0.f, 0.f, 0.f, 0.f};
  int i = s + sub;
  int a0 = adj[clampi(i)];
  int a1 = adj[clampi(i + 4)];
  int a2 = adj[clampi(i + 8)];
  int a3 = adj[clampi(i + 12)];
  uint2 r0 = ROW(a0);
  uint2 r1 = ROW(a1);
  for (; i < e; i += 8) {
    const uint2 r2 = ROW(a2), r3 = ROW(a3);  // next pair in flight
    const int a4 = adj[clampi(i + 16)];
    const int a5 = adj[clampi(i + 20)];
    {
      f32x2 p;
      p = __builtin_amdgcn_cvt_pk_f32_fp8((int)r0.x, false); acc[0] += p.x; acc[1] += p.y;
      p = __builtin_amdgcn_cvt_pk_f32_fp8((int)r0.x, true);  acc[2] += p.x; acc[3] += p.y;
      p = __builtin_amdgcn_cvt_pk_f32_fp8((int)r0.y, false); acc[4] += p.x; acc[5] += p.y;
      p = __builtin_amdgcn_cvt_pk_f32_fp8((int)r0.y, true);  acc[6] += p.x; acc[7] += p.y;
    }
    if (i + 4 < e) {
      f32x2 p;
      p = __builtin_amdgcn_cvt_pk_f32_fp8((int)r1.x, false); acc[0] += p.x; acc[1] += p.y;
      p = __builtin_amdgcn_cvt_pk_f32_fp8((int)r1.x, true);  acc[2] += p.x; acc[3] += p.y;
      p = __builtin_amdgcn_cvt_pk_f32_fp8((int)r1.y, false); acc[4] += p.x; acc[5] += p.y;
      p = __builtin_amdgcn_cvt_pk_f32_fp8((int)r1.y, true);  acc[6] += p.x; acc[7] += p.y;
    }
    r0 = r2; r1 = r3; a2 = a4; a3 = a5;
  }
#pragma unroll
  for (int o = 32; o >= 16; o >>= 1) {
#pragma unroll
    for (int k = 0; k < 8; ++k) acc[k] += __shfl_xor(acc[k], o, 64);
  }
  if (sub == 0) {
    const float inv = 1.0f / (float)max(e - s, 1);
    union { unsigned short us[8]; uint4 v; } o;
#pragma unroll
    for (int k = 0; k < 8; ++k) o.us[k] = f2bf(acc[k] * inv);
    *(uint4*)(A1 + (size_t)node * 384 + dir * 128 + cl * 8) = o.v;
  }
}

// ---------- gather-mean fp8, layer 2 (r5-measured; unchanged) ----------
__global__ __launch_bounds__(256) void gather_mean_q8_kernel(
    const unsigned char* __restrict__ Q,  // [n_nodes][256] fp8 e4m3
    __hip_bfloat16* __restrict__ A,       // A2, row stride 768
    const int* __restrict__ adjf, const int* __restrict__ offf,
    const int* __restrict__ adjb, const int* __restrict__ offb, int n_nodes) {
  const int gw = (int)(((size_t)blockIdx.x * 256 + threadIdx.x) >> 6);
  const int lane = threadIdx.x & 63;
  if (gw >= 2 * n_nodes) return;
  int node, dir;
  const int *adj, *off;
  if (gw < n_nodes) { node = gw;           adj = adjf; off = offf; dir = 0; }
  else              { node = gw - n_nodes; adj = adjb; off = offb; dir = 1; }
  const int s = off[node], e = off[node + 1];
  const int sub = lane >> 5, cl = lane & 31;
  auto clampi = [&](int i) { return max(min(i, e - 1), 0); };
  auto ROW = [&](int a) { return *(const uint2*)(Q + (size_t)a * 256 + cl * 8); };
  float acc[8] = {0.f, 0.f, 0.f, 0.f, 0.f, 0.f, 0.f, 0.f};
  int i = s + sub;
  int a0 = adj[clampi(i)];
  int a1 = adj[clampi(i + 2)];
  int a2 = adj[clampi(i + 4)];
  int a3 = adj[clampi(i + 6)];
  uint2 r0 = ROW(a0);
  uint2 r1 = ROW(a1);
  for (; i < e; i += 4) {
    const uint2 r2 = ROW(a2), r3 = ROW(a3);
    const int a4 = adj[clampi(i + 8)];
    const int a5 = adj[clampi(i + 10)];
    {
      f32x2 p;
      p = __builtin_amdgcn_cvt_pk_f32_fp8((int)r0.x, false); acc[0] += p.x; acc[1] += p.y;
      p = __builtin_amdgcn_cvt_pk_f32_fp8((int)r0.x, true);  acc[2] += p.x; acc[3] += p.y;
      p = __builtin_amdgcn_cvt_pk_f32_fp8((int)r0.y, false); acc[4] += p.x; acc[5] += p.y;
      p = __builtin_amdgcn_cvt_pk_f32_fp8((int)r0.y, true);  acc[6] += p.x; acc[7] += p.y;
    }
    if (i + 2 < e) {
      f32x2 p;
      p = __builtin_amdgcn_cvt_pk_f32_fp8((int)r1.x, false); acc[0] += p.x; acc[1] += p.y;
      p = __builtin_amdgcn_cvt_pk_f32_fp8((int)r1.x, true);  acc[2] += p.x; acc[3] += p.y;
      p = __builtin_amdgcn_cvt_pk_f32_fp8((int)r1.y, false); acc[4] += p.x; acc[5] += p.y;
      p = __builtin_amdgcn_cvt_pk_f32_fp8((int)r1.y, true);  acc[6] += p.x; acc[7] += p.y;
    }
    r0 = r2; r1 = r3; a2 = a4; a3 = a5;
  }
#pragma unroll
  for (int k = 0; k < 8; ++k) acc[k] += __shfl_xor(acc[k], 32, 64);
  if (sub == 0) {
    const float inv = 1.0f / (float)max(e - s, 1);
    union { unsigned short us[8]; uint4 v; } o;
#pragma unroll
    for (int k = 0; k < 8; ++k) o.us[k] = f2bf(acc[k] * inv);
    *(uint4*)(A + (size_t)node * 768 + dir * 256 + cl * 8) = o.v;
  }
}

// ---------- MFMA GEMM, persistent W-in-registers + counted-vmcnt ring pipeline ----------
// r10/r11 proven on K=768 (58.8 -> <46us): W hoisted to AGPRs once per block, 3-slot
// LDS ring staging tile t+2 while computing t, wait vmcnt(8) (never 0 mid-loop) so
// A-staging DMAs ride across raw s_barriers. Now templated on STORE so layer 1 (K=384,
// NIT=3, writes Cb) uses the same structure. All ring/wr indices compile-time (rule #20).
template <int K, int NBS, bool STORE>
__global__ __launch_bounds__(256, 2) void gemm_persist_kernel(
    const __hip_bfloat16* __restrict__ A, const __hip_bfloat16* __restrict__ Wpk,
    const float* __restrict__ bias, __hip_bfloat16* __restrict__ Cb,
    float* __restrict__ bnsum, float* __restrict__ bnsum2,
    unsigned* __restrict__ gmax, unsigned* __restrict__ gmin, int M, int ntiles) {
  constexpr int S = K / 16;
  constexpr int NIT = K / 128;
  static_assert(NIT % 3 == 0, "ring indexing requires NIT % 3 == 0");
  __shared__ __align__(16) union SMem {
    char at[3][16384];  // 3-slot ring: 64 rows x BK=128 x 2B each
    struct { float colsum[256], colsum2[256]; unsigned cmax[256], cmin[256]; } st;
  } sm;
  const int wave = threadIdx.x >> 6, lane = threadIdx.x & 63;
  const int cg = (int)(blockIdx.x & 1);       // col-group: cols [cg*128, cg*128+128)
  const int bstart = (int)(blockIdx.x >> 1);  // first m-tile
  const int ct = cg * 4 + wave;               // this wave's 32-col tile

  // hoist this wave's full-K W into registers (lands in AGPRs), once per block
  bf16x8 wr[S];
#pragma unroll
  for (int d = 0; d < S; ++d)
    wr[d] = *(const bf16x8*)(Wpk + ((size_t)ct * S + d) * 512 + lane * 8);

  const int col = ct * 32 + (lane & 31);
  const float bj = bias[col];
  float ls = 0.f, ls2 = 0.f, lmax = -INFINITY, lmin = INFINITY;
  const size_t rh_off = (size_t)64 * K;  // 32 rows * K * 2B (byte offset)

  int ntb = 0;
  for (int m = bstart; m < ntiles; m += NBS) ++ntb;

  auto STAGE = [&](int mi, int kb, int slot) {
    const int rbase = (bstart + mi * NBS) * 64;
    const char* gs = (const char*)(A + (size_t)(rbase + (lane & 31)) * K) + (lane >> 5) * 16;
    char* buf = sm.at[slot];
#pragma unroll
    for (int ss = 0; ss < 2; ++ss) {
      const int s = wave * 2 + ss;
      const char* g = gs + (size_t)kb * 256 + s * 32;
      load_lds16(g,          buf + (s * 2 + 0) * 1024);
      load_lds16(g + rh_off, buf + (s * 2 + 1) * 1024);
    }
  };

  if (ntb > 0) {
    STAGE(0, 0, 0);
    STAGE(0, 1, 1);
    asm volatile("s_waitcnt vmcnt(0)" ::: "memory");  // drain W-hoist + prologue stages
    __builtin_amdgcn_s_barrier();
  }

  for (int mi = 0; mi < ntb; ++mi) {
    f32x16 acc[2] = {};
#pragma unroll
    for (int kb = 0; kb < NIT; ++kb) {
      const int s_kb = (kb + 2 < NIT) ? (kb + 2) : (kb + 2 - NIT);
      const int s_mi = mi + ((kb + 2) >= NIT ? 1 : 0);
      const bool have2 = (s_mi < ntb);
      const bool have1 = !(mi == ntb - 1 && kb == NIT - 1);
      if (have2) STAGE(s_mi, s_kb, (kb + 2) % 3);
      if (have2)      asm volatile("s_waitcnt vmcnt(8)" ::: "memory");
      else if (have1) asm volatile("s_waitcnt vmcnt(4)" ::: "memory");
      else            asm volatile("s_waitcnt vmcnt(0)" ::: "memory");
      __builtin_amdgcn_sched_barrier(0);
      __builtin_amdgcn_s_barrier();  // all waves' step-t DMAs landed
      const char* ab = sm.at[kb % 3];
#pragma unroll
      for (int s = 0; s < 8; ++s) {
        const bf16x8 a0 = *(const bf16x8*)(ab + (s * 2 + 0) * 1024 + lane * 16);
        const bf16x8 a1 = *(const bf16x8*)(ab + (s * 2 + 1) * 1024 + lane * 16);
        const bf16x8 w = wr[kb * 8 + s];  // compile-time index
        acc[0] = __builtin_amdgcn_mfma_f32_32x32x16_bf16(a0, w, acc[0], 0, 0, 0);
        acc[1] = __builtin_amdgcn_mfma_f32_32x32x16_bf16(a1, w, acc[1], 0, 0, 0);
      }
      asm volatile("s_waitcnt lgkmcnt(0)" ::: "memory");  // reads of slot kb%3 complete
      __builtin_amdgcn_sched_barrier(0);
      __builtin_amdgcn_s_barrier();  // safe for step t+3 to overwrite slot kb%3
    }
    const int rbase = (bstart + mi * NBS) * 64;
#pragma unroll
    for (int rh = 0; rh < 2; ++rh) {
#pragma unroll
      for (int r = 0; r < 16; ++r) {
        const int row = rbase + rh * 32 + (r & 3) + 8 * (r >> 2) + 4 * (lane >> 5);
        if (row < M) {
          float v = acc[rh][r] + bj;
          if (STORE) Cb[(size_t)row * 768 + 512 + col] = __float2bfloat16(v);
          ls += v;
          ls2 = fmaf(v, v, ls2);
          if (!STORE) { lmax = fmaxf(lmax, v); lmin = fminf(lmin, v); }
        }
      }
    }
  }

  // single stats epilogue (LDS aliased after the loop's final barrier)
  __syncthreads();
  sm.st.colsum[threadIdx.x] = 0.f;
  sm.st.colsum2[threadIdx.x] = 0.f;
  if (!STORE) { sm.st.cmax[threadIdx.x] = 0u; sm.st.cmin[threadIdx.x] = 0u; }
  __syncthreads();
  atomicAdd(&sm.st.colsum[col], ls);
  atomicAdd(&sm.st.colsum2[col], ls2);
  if (!STORE) {
    atomicMax(&sm.st.cmax[col], fkey(lmax));
    atomicMax(&sm.st.cmin[col], ~fkey(lmin));
  }
  __syncthreads();
  atomicAdd(&bnsum[threadIdx.x], sm.st.colsum[threadIdx.x]);
  atomicAdd(&bnsum2[threadIdx.x], sm.st.colsum2[threadIdx.x]);
  if (!STORE) {
    atomicMax(&gmax[threadIdx.x], sm.st.cmax[threadIdx.x]);
    atomicMax(&gmin[threadIdx.x], sm.st.cmin[threadIdx.x]);
  }
}

// ---------- BN+ReLU in place on A2 self-slice + fp8 shadow for the layer-2 gather ----------
__global__ void bn_apply_kernel(__hip_bfloat16* __restrict__ A2,
                                unsigned char* __restrict__ A2q,
                                const float* __restrict__ sum, const float* __restrict__ sumsq,
                                const float* __restrict__ gamma, const float* __restrict__ beta,
                                int n_nodes, float inv_n) {
  const int j0 = (threadIdx.x & 63) * 4;
  const int row = blockIdx.x * 4 + (threadIdx.x >> 6);
  if (row >= n_nodes) return;
  float g[4], b[4];
#pragma unroll
  for (int k = 0; k < 4; ++k) {
    const int j = j0 + k;
    float mu = sum[j] * inv_n;
    float rs = rsqrtf(fmaxf(sumsq[j] * inv_n - mu * mu, 0.f) + BN_EPS);
    g[k] = gamma[j] * rs;
    b[k] = fmaf(-mu, g[k], beta[j]);
  }
  uint2* p = (uint2*)(A2 + (size_t)row * 768 + 512 + j0);
  uint2 w = *p;
  float h[4];
  h[0] = fmaxf(fmaf(blo(w.x), g[0], b[0]), 0.f);
  h[1] = fmaxf(fmaf(bhi(w.x), g[1], b[1]), 0.f);
  h[2] = fmaxf(fmaf(blo(w.y), g[2], b[2]), 0.f);
  h[3] = fmaxf(fmaf(bhi(w.y), g[3], b[3]), 0.f);
  unsigned short us[4] = {f2bf(h[0]), f2bf(h[1]), f2bf(h[2]), f2bf(h[3])};
  *p = *(uint2*)us;
  int q8 = __builtin_amdgcn_cvt_pk_fp8_f32(h[0], h[1], 0, false);
  q8 = __builtin_amdgcn_cvt_pk_fp8_f32(h[2], h[3], q8, true);
  *(int*)(A2q + (size_t)row * 256 + j0) = q8;
}

// ---------- finalize ----------
__global__ void finalize_kernel(const unsigned* __restrict__ xw,
                                const float* __restrict__ sum, const float* __restrict__ sumsq,
                                const unsigned* __restrict__ gmax, const unsigned* __restrict__ gmin,
                                const float* __restrict__ gamma, const float* __restrict__ beta,
                                float inv_n, void* __restrict__ out, int out_size) {
  __shared__ int votes;
  if (threadIdx.x == 0) votes = 0;
  __syncthreads();
  unsigned e = (xw[threadIdx.x] >> 7) & 0xFFu;
  if (e >= 100u && e <= 140u) atomicAdd(&votes, 1);
  __syncthreads();
  int bf = votes > 128;
  int j = threadIdx.x;
  if (j >= out_size) return;
  float mu = sum[j] * inv_n;
  float rs = rsqrtf(fmaxf(sumsq[j] * inv_n - mu * mu, 0.f) + BN_EPS);
  float g = gamma[j] * rs, b = fmaf(-mu, g, beta[j]);
  float vmax = finv(gmax[j]);
  float vmin = finv(~gmin[j]);
  float v = fmaxf(fmaf(g, (g >= 0.f) ? vmax : vmin, b), 0.f);
  if (bf) ((__hip_bfloat16*)out)[j] = __float2bfloat16(v);
  else    ((float*)out)[j] = v;
}

extern "C" void kernel_launch(void* const* d_in, const int* in_sizes, int n_in,
                              void* d_out, int out_size, void* d_ws, size_t ws_size,
                              hipStream_t stream) {
  const void* x  = d_in[0];
  const void* ei = d_in[1];
  const int n_nodes = in_sizes[0] / IN_DIM;
  const int n_edges = in_sizes[1] / 2;
  const int nb = (n_nodes + 255) / 256;
  const int Mpad = (n_nodes + 127) & ~127;

  float* ws = (float*)d_ws;
  size_t off = 0;
  auto alloc = [&](size_t n) {
    float* p = ws + off;
    off += (n + 1023) & ~(size_t)1023;
    return p;
  };
  __hip_bfloat16* Wpk1 = (__hip_bfloat16*)alloc(384 * 256 / 2);
  __hip_bfloat16* Wpk2 = (__hip_bfloat16*)alloc(768 * 256 / 2);
  float* b1      = alloc(256);
  float* b2      = alloc(256);
  float* gamma1  = alloc(256);
  float* beta1   = alloc(256);
  float* gamma2  = alloc(256);
  float* beta2   = alloc(256);
  float* zeros   = alloc(2 * (size_t)n_nodes + 2048);
  int*   degf    = (int*)zeros;
  int*   degb    = degf + n_nodes;
  float* sum1    = zeros + 2 * (size_t)n_nodes;
  float* sumsq1  = sum1 + 256;
  float* sum2    = sum1 + 512;
  float* sumsq2  = sum1 + 768;
  unsigned* max2 = (unsigned*)(sum1 + 1024);
  unsigned* min2 = (unsigned*)(sum1 + 1280);
  int*   offf    = (int*)alloc(n_nodes + 1);
  int*   offb    = (int*)alloc(n_nodes + 1);
  int*   rankf   = (int*)alloc(n_edges);
  int*   rankb   = (int*)alloc(n_edges);
  int*   adjf    = (int*)alloc(n_edges);
  int*   adjb    = (int*)alloc(n_edges);
  int*   partials = (int*)alloc(2 * nb);
  unsigned char* X8 = (unsigned char*)alloc((size_t)n_nodes * 32);  // [n][128] fp8 of x
  __hip_bfloat16* A1 = (__hip_bfloat16*)alloc((size_t)Mpad * 384 / 2);
  __hip_bfloat16* A2 = (__hip_bfloat16*)alloc((size_t)Mpad * 768 / 2);
  // fp8 shadow of h for the layer-2 gather. Aliases A1 (dead after gemm1).
  unsigned char* A2q = (unsigned char*)A1;
  (void)ws_size; (void)n_in;

  hipMemsetAsync(zeros, 0, (2 * (size_t)n_nodes + 2048) * 4, stream);

  const int pgrid = (n_edges + 255) / 256;
  prep_edges_kernel<<<pgrid, 256, 0, stream>>>(ei, degf, degb, rankf, rankb, n_edges);
  prep_x_kernel<<<pgrid, 256, 0, stream>>>(
      x,
      d_in[2], d_in[3], d_in[4], d_in[5], d_in[6], d_in[7],
      d_in[8], d_in[9], d_in[10], d_in[11], d_in[12], d_in[13],
      d_in[14], d_in[15], d_in[16], d_in[17],
      A1, X8, Wpk1, b1, Wpk2, b2, gamma1, beta1, gamma2, beta2, n_nodes);

  scan_part_kernel<<<2 * nb, 256, 0, stream>>>(degf, degb, offf, offb, partials, n_nodes, nb);
  scan_add_kernel<<<2 * nb, 256, 0, stream>>>(offf, offb, partials, n_nodes, nb, n_edges);
  fill_adj_kernel<<<(n_edges + 255) / 256, 256, 0, stream>>>(
      ei, rankf, rankb, offf, offb, adjf, adjb, n_edges);

  const float inv_n = 1.0f / (float)n_nodes;
  const int ggrid = (2 * n_nodes + 3) / 4;

  // ---- layer 1 (fp8-source gather, persistent W-in-reg GEMM with C store) ----
  gather_mean_x8_kernel<<<ggrid, 256, 0, stream>>>(
      X8, A1, adjf, offf, adjb, offb, n_nodes);
  gemm_persist_kernel<384, 256, true><<<2 * 256, 256, 0, stream>>>(
      A1, Wpk1, b1, A2, sum1, sumsq1, max2, min2, n_nodes, Mpad / 64);
  bn_apply_kernel<<<(n_nodes + 3) / 4, 256, 0, stream>>>(
      A2, A2q, sum1, sumsq1, gamma1, beta1, n_nodes, inv_n);

  // ---- layer 2 (fp8-source gather, persistent counted-vmcnt GEMM) ----
  gather_mean_q8_kernel<<<ggrid, 256, 0, stream>>>(
      A2q, A2, adjf, offf, adjb, offb, n_nodes);
  gemm_persist_kernel<768, 256, false><<<2 * 256, 256, 0, stream>>>(
      A2, Wpk2, b2, nullptr, sum2, sumsq2, max2, min2, n_nodes, Mpad / 64);
  finalize_kernel<<<1, 256, 0, stream>>>(
      (const unsigned*)x, sum2, sumsq2, max2, min2, gamma2, beta2, inv_n, d_out, out_size);
}

// Round 13
// 318.281 us; speedup vs baseline: 1.1427x; 1.0093x over previous
//
#include <hip/hip_runtime.h>
#include <hip/hip_bf16.h>

#define IN_DIM 128
#define HID 256
#define BN_EPS 1e-5f

typedef __attribute__((ext_vector_type(8))) short bf16x8;
typedef __attribute__((ext_vector_type(16))) float f32x16;
typedef __attribute__((ext_vector_type(2))) float f32x2;

// ---------- helpers ----------
__device__ __forceinline__ float ld_f(const void* p, size_t i, int bf16) {
  if (bf16) return __bfloat162float(((const __hip_bfloat16*)p)[i]);
  return ((const float*)p)[i];
}
__device__ __forceinline__ float blo(unsigned u) { return __uint_as_float(u << 16); }
__device__ __forceinline__ float bhi(unsigned u) { return __uint_as_float(u & 0xffff0000u); }
__device__ __forceinline__ unsigned short f2bf(float f) {
  __hip_bfloat16 b = __float2bfloat16(f);
  return __builtin_bit_cast(unsigned short, b);
}
__device__ __forceinline__ void load_lds16(const void* g, void* l) {
  __builtin_amdgcn_global_load_lds((const __attribute__((address_space(1))) void*)g,
                                   (__attribute__((address_space(3))) void*)l, 16, 0, 0);
}
// order-preserving float->uint key (monotone increasing); init 0 is neutral for max
__device__ __forceinline__ unsigned fkey(float v) {
  unsigned s = __float_as_uint(v);
  return (s & 0x80000000u) ? ~s : (s | 0x80000000u);
}
__device__ __forceinline__ float finv(unsigned k) {
  unsigned s = (k & 0x80000000u) ? (k ^ 0x80000000u) : ~k;
  return __uint_as_float(s);
}

// ---------- prep A: edge histogram + per-edge rank (atomic return value) ----------
__global__ void prep_edges_kernel(
    const void* __restrict__ ei,
    int* __restrict__ degf, int* __restrict__ degb,
    int* __restrict__ rankf, int* __restrict__ rankb, int n_edges) {
  __shared__ int nz;
  if (threadIdx.x == 0) nz = 0;
  __syncthreads();
  if (((const unsigned*)ei)[2 * threadIdx.x + 1] != 0u) atomicAdd(&nz, 1);
  __syncthreads();
  const int i32 = nz > 0;
  const int tid = blockIdx.x * 256 + threadIdx.x;
  const int nt = gridDim.x * 256;
  for (int i = tid; i < n_edges; i += nt) {
    int s, d;
    if (i32) { s = ((const int*)ei)[i]; d = ((const int*)ei)[n_edges + i]; }
    else     { s = (int)((const long long*)ei)[i]; d = (int)((const long long*)ei)[n_edges + i]; }
    rankf[i] = atomicAdd(&degf[d], 1);
    rankb[i] = atomicAdd(&degb[s], 1);
  }
}

// ---------- prep B: x -> A1 self-slice (bf16) + X8 (fp8) + W packs + biases ----------
__global__ void prep_x_kernel(
    const void* __restrict__ x,
    const void* Wl_f1, const void* bl_f1, const void* Wr_f1,
    const void* Wl_b1, const void* bl_b1, const void* Wr_b1,
    const void* Wl_f2, const void* bl_f2, const void* Wr_f2,
    const void* Wl_b2, const void* bl_b2, const void* Wr_b2,
    const void* g1, const void* be1, const void* g2, const void* be2,
    __hip_bfloat16* __restrict__ A1,
    unsigned char* __restrict__ X8,
    __hip_bfloat16* __restrict__ Wpk1, float* __restrict__ b1,
    __hip_bfloat16* __restrict__ Wpk2, float* __restrict__ b2,
    float* __restrict__ gamma1, float* __restrict__ beta1,
    float* __restrict__ gamma2, float* __restrict__ beta2,
    int n_nodes) {
  __shared__ int votes;
  if (threadIdx.x == 0) votes = 0;
  __syncthreads();
  {
    unsigned e = (((const unsigned*)x)[threadIdx.x] >> 7) & 0xFFu;
    if (e >= 100u && e <= 140u) atomicAdd(&votes, 1);
  }
  __syncthreads();
  const int bf = (votes > 128) ? 1 : 0;
  const int tid = blockIdx.x * 256 + threadIdx.x;
  const int nt = gridDim.x * 256;
  const size_t nq = (size_t)n_nodes * IN_DIM / 4;
  for (size_t q = tid; q < nq; q += nt) {
    const int row = (int)(q >> 5), j = (int)(q & 31) * 4;
    __hip_bfloat16* dstp = A1 + (size_t)row * 384 + 256 + j;
    float f0, f1, f2, f3;
    if (bf) {
      uint2 v = ((const uint2*)x)[q];
      *(uint2*)dstp = v;
      f0 = blo(v.x); f1 = bhi(v.x); f2 = blo(v.y); f3 = bhi(v.y);
    } else {
      float4 v = ((const float4*)x)[q];
      unsigned short o[4] = {f2bf(v.x), f2bf(v.y), f2bf(v.z), f2bf(v.w)};
      *(uint2*)dstp = *(uint2*)o;
      f0 = v.x; f1 = v.y; f2 = v.z; f3 = v.w;
    }
    int p8 = __builtin_amdgcn_cvt_pk_fp8_f32(f0, f1, 0, false);
    p8 = __builtin_amdgcn_cvt_pk_fp8_f32(f2, f3, p8, true);
    *(int*)(X8 + (size_t)row * 128 + j) = p8;
  }
  for (int idx = tid; idx < 768 * 256; idx += nt) {
    {
      int j = idx & 7, l = (idx >> 3) & 63, rest = idx >> 9;
      int s = rest % 48, t = rest / 48;
      int k = s * 16 + (l >> 5) * 8 + j, col = t * 32 + (l & 31);
      float v;
      if (k < 256)      v = ld_f(Wl_f2, (size_t)k * 256 + col, bf);
      else if (k < 512) v = ld_f(Wl_b2, (size_t)(k - 256) * 256 + col, bf);
      else              v = ld_f(Wr_f2, (size_t)(k - 512) * 256 + col, bf) +
                            ld_f(Wr_b2, (size_t)(k - 512) * 256 + col, bf);
      Wpk2[idx] = __float2bfloat16(v);
    }
    if (idx < 384 * 256) {
      int j = idx & 7, l = (idx >> 3) & 63, rest = idx >> 9;
      int s = rest % 24, t = rest / 24;
      int k = s * 16 + (l >> 5) * 8 + j, col = t * 32 + (l & 31);
      float v;
      if (k < 128)      v = ld_f(Wl_f1, (size_t)k * 256 + col, bf);
      else if (k < 256) v = ld_f(Wl_b1, (size_t)(k - 128) * 256 + col, bf);
      else              v = ld_f(Wr_f1, (size_t)(k - 256) * 256 + col, bf) +
                            ld_f(Wr_b1, (size_t)(k - 256) * 256 + col, bf);
      Wpk1[idx] = __float2bfloat16(v);
    }
    if (idx < 256) {
      b1[idx] = ld_f(bl_f1, idx, bf) + ld_f(bl_b1, idx, bf);
      b2[idx] = ld_f(bl_f2, idx, bf) + ld_f(bl_b2, idx, bf);
      gamma1[idx] = ld_f(g1, idx, bf);
      beta1[idx]  = ld_f(be1, idx, bf);
      gamma2[idx] = ld_f(g2, idx, bf);
      beta2[idx]  = ld_f(be2, idx, bf);
    }
  }
}

// ---------- CSR build ----------
__global__ void scan_part_kernel(const int* __restrict__ degf, const int* __restrict__ degb,
                                 int* __restrict__ offf, int* __restrict__ offb,
                                 int* __restrict__ partials, int n, int nb) {
  __shared__ int buf[256];
  const int b = blockIdx.x;
  const int* deg = (b < nb) ? degf : degb;
  int* off = (b < nb) ? offf : offb;
  const int chunk = (b < nb) ? b : (b - nb);
  const int i = chunk * 256 + threadIdx.x;
  int v = (i < n) ? deg[i] : 0;
  buf[threadIdx.x] = v;
  __syncthreads();
  for (int s = 1; s < 256; s <<= 1) {
    int t = (threadIdx.x >= s) ? buf[threadIdx.x - s] : 0;
    __syncthreads();
    buf[threadIdx.x] += t;
    __syncthreads();
  }
  if (i < n) off[i] = buf[threadIdx.x] - v;
  if (threadIdx.x == 255) partials[b] = buf[255];
}

__global__ void scan_add_kernel(int* __restrict__ offf, int* __restrict__ offb,
                                const int* __restrict__ partials, int n, int nb, int n_edges) {
  __shared__ int red[256];
  const int b = blockIdx.x;
  int* off = (b < nb) ? offf : offb;
  const int chunk = (b < nb) ? b : (b - nb);
  const int abase = (b < nb) ? 0 : nb;
  int v = (threadIdx.x < chunk) ? partials[abase + threadIdx.x] : 0;
  red[threadIdx.x] = v;
  __syncthreads();
  for (int s = 128; s > 0; s >>= 1) {
    if (threadIdx.x < s) red[threadIdx.x] += red[threadIdx.x + s];
    __syncthreads();
  }
  const int prefix = red[0];
  const int i = chunk * 256 + threadIdx.x;
  if (i < n) off[i] += prefix;
  if (b == 0 && threadIdx.x == 0) { offf[n] = n_edges; offb[n] = n_edges; }
}

// ---------- atomic-free edge placement ----------
__global__ void fill_adj_kernel(const void* __restrict__ ei,
                                const int* __restrict__ rankf, const int* __restrict__ rankb,
                                const int* __restrict__ offf, const int* __restrict__ offb,
                                int* __restrict__ adjf, int* __restrict__ adjb, int n_edges) {
  __shared__ int nz;
  if (threadIdx.x == 0) nz = 0;
  __syncthreads();
  if (((const unsigned*)ei)[2 * threadIdx.x + 1] != 0u) atomicAdd(&nz, 1);
  __syncthreads();
  const int i32 = nz > 0;
  int i = blockIdx.x * 256 + threadIdx.x;
  if (i >= n_edges) return;
  int s, d;
  if (i32) { s = ((const int*)ei)[i]; d = ((const int*)ei)[n_edges + i]; }
  else     { s = (int)((const long long*)ei)[i]; d = (int)((const long long*)ei)[n_edges + i]; }
  adjf[offf[d] + rankf[i]] = s;
  adjb[offb[s] + rankb[i]] = d;
}

// ---------- gather-mean fp8, layer 1: X8[n][128] -> bf16 mean slices of A1 ----------
// r12: packed-f32 accumulation (f32x2 acc -> v_pk_add_f32) halves the add count in the
// unpack chain (VALUBusy 61% showed the gathers are VALU-co-limited after fp8 halved
// their traffic). Same arithmetic order -> bit-identical output.
__global__ __launch_bounds__(256) void gather_mean_x8_kernel(
    const unsigned char* __restrict__ Q,  // [n_nodes][128] fp8 e4m3
    __hip_bfloat16* __restrict__ A1,      // row stride 384
    const int* __restrict__ adjf, const int* __restrict__ offf,
    const int* __restrict__ adjb, const int* __restrict__ offb, int n_nodes) {
  const int gw = (int)(((size_t)blockIdx.x * 256 + threadIdx.x) >> 6);
  const int lane = threadIdx.x & 63;
  if (gw >= 2 * n_nodes) return;
  int node, dir;
  const int *adj, *off;
  if (gw < n_nodes) { node = gw;           adj = adjf; off = offf; dir = 0; }
  else              { node = gw - n_nodes; adj = adjb; off = offb; dir = 1; }
  const int s = off[node], e = off[node + 1];
  const int sub = lane >> 4, cl = lane & 15;  // 4 subs x 16 col-lanes (8 cols each)
  auto clampi = [&](int i) { return max(min(i, e - 1), 0); };
  auto ROW = [&](int a) { return *(const uint2*)(Q + (size_t)a * 128 + cl * 8); };
  f32x2 acc2[4] = {};
  int i = s + sub;
  int a0 = adj[clampi(i)];
  int a1 = adj[clampi(i + 4)];
  int a2 = adj[clampi(i + 8)];
  int a3 = adj[clampi(i + 12)];
  uint2 r0 = ROW(a0);
  uint2 r1 = ROW(a1);
  for (; i < e; i += 8) {
    const uint2 r2 = ROW(a2), r3 = ROW(a3);  // next pair in flight
    const int a4 = adj[clampi(i + 16)];
    const int a5 = adj[clampi(i + 20)];
    acc2[0] += __builtin_amdgcn_cvt_pk_f32_fp8((int)r0.x, false);
    acc2[1] += __builtin_amdgcn_cvt_pk_f32_fp8((int)r0.x, true);
    acc2[2] += __builtin_amdgcn_cvt_pk_f32_fp8((int)r0.y, false);
    acc2[3] += __builtin_amdgcn_cvt_pk_f32_fp8((int)r0.y, true);
    if (i + 4 < e) {
      acc2[0] += __builtin_amdgcn_cvt_pk_f32_fp8((int)r1.x, false);
      acc2[1] += __builtin_amdgcn_cvt_pk_f32_fp8((int)r1.x, true);
      acc2[2] += __builtin_amdgcn_cvt_pk_f32_fp8((int)r1.y, false);
      acc2[3] += __builtin_amdgcn_cvt_pk_f32_fp8((int)r1.y, true);
    }
    r0 = r2; r1 = r3; a2 = a4; a3 = a5;
  }
  float acc[8] = {acc2[0].x, acc2[0].y, acc2[1].x, acc2[1].y,
                  acc2[2].x, acc2[2].y, acc2[3].x, acc2[3].y};
#pragma unroll
  for (int o = 32; o >= 16; o >>= 1) {
#pragma unroll
    for (int k = 0; k < 8; ++k) acc[k] += __shfl_xor(acc[k], o, 64);
  }
  if (sub == 0) {
    const float inv = 1.0f / (float)max(e - s, 1);
    union { unsigned short us[8]; uint4 v; } o;
#pragma unroll
    for (int k = 0; k < 8; ++k) o.us[k] = f2bf(acc[k] * inv);
    *(uint4*)(A1 + (size_t)node * 384 + dir * 128 + cl * 8) = o.v;
  }
}

// ---------- gather-mean fp8, layer 2 (packed-f32 accumulation, r12) ----------
__global__ __launch_bounds__(256) void gather_mean_q8_kernel(
    const unsigned char* __restrict__ Q,  // [n_nodes][256] fp8 e4m3
    __hip_bfloat16* __restrict__ A,       // A2, row stride 768
    const int* __restrict__ adjf, const int* __restrict__ offf,
    const int* __restrict__ adjb, const int* __restrict__ offb, int n_nodes) {
  const int gw = (int)(((size_t)blockIdx.x * 256 + threadIdx.x) >> 6);
  const int lane = threadIdx.x & 63;
  if (gw >= 2 * n_nodes) return;
  int node, dir;
  const int *adj, *off;
  if (gw < n_nodes) { node = gw;           adj = adjf; off = offf; dir = 0; }
  else              { node = gw - n_nodes; adj = adjb; off = offb; dir = 1; }
  const int s = off[node], e = off[node + 1];
  const int sub = lane >> 5, cl = lane & 31;
  auto clampi = [&](int i) { return max(min(i, e - 1), 0); };
  auto ROW = [&](int a) { return *(const uint2*)(Q + (size_t)a * 256 + cl * 8); };
  f32x2 acc2[4] = {};
  int i = s + sub;
  int a0 = adj[clampi(i)];
  int a1 = adj[clampi(i + 2)];
  int a2 = adj[clampi(i + 4)];
  int a3 = adj[clampi(i + 6)];
  uint2 r0 = ROW(a0);
  uint2 r1 = ROW(a1);
  for (; i < e; i += 4) {
    const uint2 r2 = ROW(a2), r3 = ROW(a3);
    const int a4 = adj[clampi(i + 8)];
    const int a5 = adj[clampi(i + 10)];
    acc2[0] += __builtin_amdgcn_cvt_pk_f32_fp8((int)r0.x, false);
    acc2[1] += __builtin_amdgcn_cvt_pk_f32_fp8((int)r0.x, true);
    acc2[2] += __builtin_amdgcn_cvt_pk_f32_fp8((int)r0.y, false);
    acc2[3] += __builtin_amdgcn_cvt_pk_f32_fp8((int)r0.y, true);
    if (i + 2 < e) {
      acc2[0] += __builtin_amdgcn_cvt_pk_f32_fp8((int)r1.x, false);
      acc2[1] += __builtin_amdgcn_cvt_pk_f32_fp8((int)r1.x, true);
      acc2[2] += __builtin_amdgcn_cvt_pk_f32_fp8((int)r1.y, false);
      acc2[3] += __builtin_amdgcn_cvt_pk_f32_fp8((int)r1.y, true);
    }
    r0 = r2; r1 = r3; a2 = a4; a3 = a5;
  }
  float acc[8] = {acc2[0].x, acc2[0].y, acc2[1].x, acc2[1].y,
                  acc2[2].x, acc2[2].y, acc2[3].x, acc2[3].y};
#pragma unroll
  for (int k = 0; k < 8; ++k) acc[k] += __shfl_xor(acc[k], 32, 64);
  if (sub == 0) {
    const float inv = 1.0f / (float)max(e - s, 1);
    union { unsigned short us[8]; uint4 v; } o;
#pragma unroll
    for (int k = 0; k < 8; ++k) o.us[k] = f2bf(acc[k] * inv);
    *(uint4*)(A + (size_t)node * 768 + dir * 256 + cl * 8) = o.v;
  }
}

// ---------- MFMA GEMM, persistent W-in-registers + counted-vmcnt ring pipeline ----------
// r10/r11 proven: W hoisted to AGPRs once per block, 3-slot LDS ring staging tile t+2
// while computing t, wait vmcnt(8) (never 0 mid-loop) so A-staging DMAs ride across raw
// s_barriers. Templated on STORE for layer 1 (K=384, writes Cb). All ring/wr indices
// compile-time (rule #20).
template <int K, int NBS, bool STORE>
__global__ __launch_bounds__(256, 2) void gemm_persist_kernel(
    const __hip_bfloat16* __restrict__ A, const __hip_bfloat16* __restrict__ Wpk,
    const float* __restrict__ bias, __hip_bfloat16* __restrict__ Cb,
    float* __restrict__ bnsum, float* __restrict__ bnsum2,
    unsigned* __restrict__ gmax, unsigned* __restrict__ gmin, int M, int ntiles) {
  constexpr int S = K / 16;
  constexpr int NIT = K / 128;
  static_assert(NIT % 3 == 0, "ring indexing requires NIT % 3 == 0");
  __shared__ __align__(16) union SMem {
    char at[3][16384];  // 3-slot ring: 64 rows x BK=128 x 2B each
    struct { float colsum[256], colsum2[256]; unsigned cmax[256], cmin[256]; } st;
  } sm;
  const int wave = threadIdx.x >> 6, lane = threadIdx.x & 63;
  const int cg = (int)(blockIdx.x & 1);       // col-group: cols [cg*128, cg*128+128)
  const int bstart = (int)(blockIdx.x >> 1);  // first m-tile
  const int ct = cg * 4 + wave;               // this wave's 32-col tile

  // hoist this wave's full-K W into registers (lands in AGPRs), once per block
  bf16x8 wr[S];
#pragma unroll
  for (int d = 0; d < S; ++d)
    wr[d] = *(const bf16x8*)(Wpk + ((size_t)ct * S + d) * 512 + lane * 8);

  const int col = ct * 32 + (lane & 31);
  const float bj = bias[col];
  float ls = 0.f, ls2 = 0.f, lmax = -INFINITY, lmin = INFINITY;
  const size_t rh_off = (size_t)64 * K;  // 32 rows * K * 2B (byte offset)

  int ntb = 0;
  for (int m = bstart; m < ntiles; m += NBS) ++ntb;

  auto STAGE = [&](int mi, int kb, int slot) {
    const int rbase = (bstart + mi * NBS) * 64;
    const char* gs = (const char*)(A + (size_t)(rbase + (lane & 31)) * K) + (lane >> 5) * 16;
    char* buf = sm.at[slot];
#pragma unroll
    for (int ss = 0; ss < 2; ++ss) {
      const int s = wave * 2 + ss;
      const char* g = gs + (size_t)kb * 256 + s * 32;
      load_lds16(g,          buf + (s * 2 + 0) * 1024);
      load_lds16(g + rh_off, buf + (s * 2 + 1) * 1024);
    }
  };

  if (ntb > 0) {
    STAGE(0, 0, 0);
    STAGE(0, 1, 1);
    asm volatile("s_waitcnt vmcnt(0)" ::: "memory");  // drain W-hoist + prologue stages
    __builtin_amdgcn_s_barrier();
  }

  for (int mi = 0; mi < ntb; ++mi) {
    f32x16 acc[2] = {};
#pragma unroll
    for (int kb = 0; kb < NIT; ++kb) {
      const int s_kb = (kb + 2 < NIT) ? (kb + 2) : (kb + 2 - NIT);
      const int s_mi = mi + ((kb + 2) >= NIT ? 1 : 0);
      const bool have2 = (s_mi < ntb);
      const bool have1 = !(mi == ntb - 1 && kb == NIT - 1);
      if (have2) STAGE(s_mi, s_kb, (kb + 2) % 3);
      if (have2)      asm volatile("s_waitcnt vmcnt(8)" ::: "memory");
      else if (have1) asm volatile("s_waitcnt vmcnt(4)" ::: "memory");
      else            asm volatile("s_waitcnt vmcnt(0)" ::: "memory");
      __builtin_amdgcn_sched_barrier(0);
      __builtin_amdgcn_s_barrier();  // all waves' step-t DMAs landed
      const char* ab = sm.at[kb % 3];
#pragma unroll
      for (int s = 0; s < 8; ++s) {
        const bf16x8 a0 = *(const bf16x8*)(ab + (s * 2 + 0) * 1024 + lane * 16);
        const bf16x8 a1 = *(const bf16x8*)(ab + (s * 2 + 1) * 1024 + lane * 16);
        const bf16x8 w = wr[kb * 8 + s];  // compile-time index
        acc[0] = __builtin_amdgcn_mfma_f32_32x32x16_bf16(a0, w, acc[0], 0, 0, 0);
        acc[1] = __builtin_amdgcn_mfma_f32_32x32x16_bf16(a1, w, acc[1], 0, 0, 0);
      }
      asm volatile("s_waitcnt lgkmcnt(0)" ::: "memory");  // reads of slot kb%3 complete
      __builtin_amdgcn_sched_barrier(0);
      __builtin_amdgcn_s_barrier();  // safe for step t+3 to overwrite slot kb%3
    }
    const int rbase = (bstart + mi * NBS) * 64;
#pragma unroll
    for (int rh = 0; rh < 2; ++rh) {
#pragma unroll
      for (int r = 0; r < 16; ++r) {
        const int row = rbase + rh * 32 + (r & 3) + 8 * (r >> 2) + 4 * (lane >> 5);
        if (row < M) {
          float v = acc[rh][r] + bj;
          if (STORE) Cb[(size_t)row * 768 + 512 + col] = __float2bfloat16(v);
          ls += v;
          ls2 = fmaf(v, v, ls2);
          if (!STORE) { lmax = fmaxf(lmax, v); lmin = fminf(lmin, v); }
        }
      }
    }
  }

  // single stats epilogue (LDS aliased after the loop's final barrier)
  __syncthreads();
  sm.st.colsum[threadIdx.x] = 0.f;
  sm.st.colsum2[threadIdx.x] = 0.f;
  if (!STORE) { sm.st.cmax[threadIdx.x] = 0u; sm.st.cmin[threadIdx.x] = 0u; }
  __syncthreads();
  atomicAdd(&sm.st.colsum[col], ls);
  atomicAdd(&sm.st.colsum2[col], ls2);
  if (!STORE) {
    atomicMax(&sm.st.cmax[col], fkey(lmax));
    atomicMax(&sm.st.cmin[col], ~fkey(lmin));
  }
  __syncthreads();
  atomicAdd(&bnsum[threadIdx.x], sm.st.colsum[threadIdx.x]);
  atomicAdd(&bnsum2[threadIdx.x], sm.st.colsum2[threadIdx.x]);
  if (!STORE) {
    atomicMax(&gmax[threadIdx.x], sm.st.cmax[threadIdx.x]);
    atomicMax(&gmin[threadIdx.x], sm.st.cmin[threadIdx.x]);
  }
}

// ---------- BN+ReLU in place on A2 self-slice + fp8 shadow for the layer-2 gather ----------
__global__ void bn_apply_kernel(__hip_bfloat16* __restrict__ A2,
                                unsigned char* __restrict__ A2q,
                                const float* __restrict__ sum, const float* __restrict__ sumsq,
                                const float* __restrict__ gamma, const float* __restrict__ beta,
                                int n_nodes, float inv_n) {
  const int j0 = (threadIdx.x & 63) * 4;
  const int row = blockIdx.x * 4 + (threadIdx.x >> 6);
  if (row >= n_nodes) return;
  float g[4], b[4];
#pragma unroll
  for (int k = 0; k < 4; ++k) {
    const int j = j0 + k;
    float mu = sum[j] * inv_n;
    float rs = rsqrtf(fmaxf(sumsq[j] * inv_n - mu * mu, 0.f) + BN_EPS);
    g[k] = gamma[j] * rs;
    b[k] = fmaf(-mu, g[k], beta[j]);
  }
  uint2* p = (uint2*)(A2 + (size_t)row * 768 + 512 + j0);
  uint2 w = *p;
  float h[4];
  h[0] = fmaxf(fmaf(blo(w.x), g[0], b[0]), 0.f);
  h[1] = fmaxf(fmaf(bhi(w.x), g[1], b[1]), 0.f);
  h[2] = fmaxf(fmaf(blo(w.y), g[2], b[2]), 0.f);
  h[3] = fmaxf(fmaf(bhi(w.y), g[3], b[3]), 0.f);
  unsigned short us[4] = {f2bf(h[0]), f2bf(h[1]), f2bf(h[2]), f2bf(h[3])};
  *p = *(uint2*)us;
  int q8 = __builtin_amdgcn_cvt_pk_fp8_f32(h[0], h[1], 0, false);
  q8 = __builtin_amdgcn_cvt_pk_fp8_f32(h[2], h[3], q8, true);
  *(int*)(A2q + (size_t)row * 256 + j0) = q8;
}

// ---------- finalize ----------
__global__ void finalize_kernel(const unsigned* __restrict__ xw,
                                const float* __restrict__ sum, const float* __restrict__ sumsq,
                                const unsigned* __restrict__ gmax, const unsigned* __restrict__ gmin,
                                const float* __restrict__ gamma, const float* __restrict__ beta,
                                float inv_n, void* __restrict__ out, int out_size) {
  __shared__ int votes;
  if (threadIdx.x == 0) votes = 0;
  __syncthreads();
  unsigned e = (xw[threadIdx.x] >> 7) & 0xFFu;
  if (e >= 100u && e <= 140u) atomicAdd(&votes, 1);
  __syncthreads();
  int bf = votes > 128;
  int j = threadIdx.x;
  if (j >= out_size) return;
  float mu = sum[j] * inv_n;
  float rs = rsqrtf(fmaxf(sumsq[j] * inv_n - mu * mu, 0.f) + BN_EPS);
  float g = gamma[j] * rs, b = fmaf(-mu, g, beta[j]);
  float vmax = finv(gmax[j]);
  float vmin = finv(~gmin[j]);
  float v = fmaxf(fmaf(g, (g >= 0.f) ? vmax : vmin, b), 0.f);
  if (bf) ((__hip_bfloat16*)out)[j] = __float2bfloat16(v);
  else    ((float*)out)[j] = v;
}

extern "C" void kernel_launch(void* const* d_in, const int* in_sizes, int n_in,
                              void* d_out, int out_size, void* d_ws, size_t ws_size,
                              hipStream_t stream) {
  const void* x  = d_in[0];
  const void* ei = d_in[1];
  const int n_nodes = in_sizes[0] / IN_DIM;
  const int n_edges = in_sizes[1] / 2;
  const int nb = (n_nodes + 255) / 256;
  const int Mpad = (n_nodes + 127) & ~127;

  float* ws = (float*)d_ws;
  size_t off = 0;
  auto alloc = [&](size_t n) {
    float* p = ws + off;
    off += (n + 1023) & ~(size_t)1023;
    return p;
  };
  __hip_bfloat16* Wpk1 = (__hip_bfloat16*)alloc(384 * 256 / 2);
  __hip_bfloat16* Wpk2 = (__hip_bfloat16*)alloc(768 * 256 / 2);
  float* b1      = alloc(256);
  float* b2      = alloc(256);
  float* gamma1  = alloc(256);
  float* beta1   = alloc(256);
  float* gamma2  = alloc(256);
  float* beta2   = alloc(256);
  float* zeros   = alloc(2 * (size_t)n_nodes + 2048);
  int*   degf    = (int*)zeros;
  int*   degb    = degf + n_nodes;
  float* sum1    = zeros + 2 * (size_t)n_nodes;
  float* sumsq1  = sum1 + 256;
  float* sum2    = sum1 + 512;
  float* sumsq2  = sum1 + 768;
  unsigned* max2 = (unsigned*)(sum1 + 1024);
  unsigned* min2 = (unsigned*)(sum1 + 1280);
  int*   offf    = (int*)alloc(n_nodes + 1);
  int*   offb    = (int*)alloc(n_nodes + 1);
  int*   rankf   = (int*)alloc(n_edges);
  int*   rankb   = (int*)alloc(n_edges);
  int*   adjf    = (int*)alloc(n_edges);
  int*   adjb    = (int*)alloc(n_edges);
  int*   partials = (int*)alloc(2 * nb);
  unsigned char* X8 = (unsigned char*)alloc((size_t)n_nodes * 32);  // [n][128] fp8 of x
  __hip_bfloat16* A1 = (__hip_bfloat16*)alloc((size_t)Mpad * 384 / 2);
  __hip_bfloat16* A2 = (__hip_bfloat16*)alloc((size_t)Mpad * 768 / 2);
  // fp8 shadow of h for the layer-2 gather. Aliases A1 (dead after gemm1).
  unsigned char* A2q = (unsigned char*)A1;
  (void)ws_size; (void)n_in;

  hipMemsetAsync(zeros, 0, (2 * (size_t)n_nodes + 2048) * 4, stream);

  const int pgrid = (n_edges + 255) / 256;
  prep_edges_kernel<<<pgrid, 256, 0, stream>>>(ei, degf, degb, rankf, rankb, n_edges);
  prep_x_kernel<<<pgrid, 256, 0, stream>>>(
      x,
      d_in[2], d_in[3], d_in[4], d_in[5], d_in[6], d_in[7],
      d_in[8], d_in[9], d_in[10], d_in[11], d_in[12], d_in[13],
      d_in[14], d_in[15], d_in[16], d_in[17],
      A1, X8, Wpk1, b1, Wpk2, b2, gamma1, beta1, gamma2, beta2, n_nodes);

  scan_part_kernel<<<2 * nb, 256, 0, stream>>>(degf, degb, offf, offb, partials, n_nodes, nb);
  scan_add_kernel<<<2 * nb, 256, 0, stream>>>(offf, offb, partials, n_nodes, nb, n_edges);
  fill_adj_kernel<<<(n_edges + 255) / 256, 256, 0, stream>>>(
      ei, rankf, rankb, offf, offb, adjf, adjb, n_edges);

  const float inv_n = 1.0f / (float)n_nodes;
  const int ggrid = (2 * n_nodes + 3) / 4;

  // ---- layer 1 (fp8-source gather, persistent W-in-reg GEMM with C store) ----
  gather_mean_x8_kernel<<<ggrid, 256, 0, stream>>>(
      X8, A1, adjf, offf, adjb, offb, n_nodes);
  gemm_persist_kernel<384, 256, true><<<2 * 256, 256, 0, stream>>>(
      A1, Wpk1, b1, A2, sum1, sumsq1, max2, min2, n_nodes, Mpad / 64);
  bn_apply_kernel<<<(n_nodes + 3) / 4, 256, 0, stream>>>(
      A2, A2q, sum1, sumsq1, gamma1, beta1, n_nodes, inv_n);

  // ---- layer 2 (fp8-source gather, persistent counted-vmcnt GEMM) ----
  gather_mean_q8_kernel<<<ggrid, 256, 0, stream>>>(
      A2q, A2, adjf, offf, adjb, offb, n_nodes);
  gemm_persist_kernel<768, 256, false><<<2 * 256, 256, 0, stream>>>(
      A2, Wpk2, b2, nullptr, sum2, sumsq2, max2, min2, n_nodes, Mpad / 64);
  finalize_kernel<<<1, 256, 0, stream>>>(
      (const unsigned*)x, sum2, sumsq2, max2, min2, gamma2, beta2, inv_n, d_out, out_size);
}